// Round 8
// baseline (435.973 us; speedup 1.0000x reference)
//
#include <hip/hip_runtime.h>

typedef unsigned short u16;
typedef __attribute__((ext_vector_type(8))) short short8;
typedef __attribute__((ext_vector_type(4))) float floatx4;

#define B_  16
#define S_  384
#define D_  768
#define H_  12
#define DH_ 64
#define FF_ 3072

__device__ __forceinline__ float b2f(u16 h) { return __uint_as_float(((unsigned)h) << 16); }
__device__ __forceinline__ u16 f2b(float f) {
  unsigned u = __float_as_uint(f);
  u += 0x7fffu + ((u >> 16) & 1u);
  return (u16)(u >> 16);
}

__device__ __forceinline__ void gload16(const u16* g, u16* l) {
  __builtin_amdgcn_global_load_lds(
      (const __attribute__((address_space(1))) unsigned int*)g,
      (__attribute__((address_space(3))) unsigned int*)l, 16, 0, 0);
}

__global__ __launch_bounds__(256) void fill_sentinel(u16* out, int n) {
  int i = blockIdx.x * 256 + threadIdx.x;
  if (i < n) out[i] = 0x42DE;  // bf16 111.0
}

// inline dtype detect: 256 u16 of x; fp32 low-halves hit exp>=0xC0 w.p. 0.25
__device__ __forceinline__ int detect_flag(const u16* x, int tid, int* sh) {
  const unsigned e = (x[tid] >> 7) & 0xFFu;
  const unsigned long long m = __ballot(e >= 0xC0u);
  if ((tid & 63) == 0) sh[tid >> 6] = (m != 0ull) ? 1 : 0;
  __syncthreads();
  return sh[0] | sh[1] | sh[2] | sh[3];
}

// ---------------- mega-preamble: transposes + converts + flag, ONE dispatch ----------------
struct TP { const void* src[7]; u16* dst[7]; };
__global__ __launch_bounds__(256) void preamble_all(
    TP tp, const void* x, const void* pe,
    const void* b1, const void* ub, const void* vb, const void* b2,
    const void* g1, const void* be1, const void* g2, const void* be2,
    u16* xb, u16* peb,
    u16* b1c, u16* ubc, u16* vbc, u16* b2c,
    u16* g1c, u16* be1c, u16* g2c, u16* be2c, int* flag_ws) {
  __shared__ u16 t[32][33];
  __shared__ int fl[4];
  const int tid = threadIdx.x;
  const int f32 = detect_flag((const u16*)x, tid, fl);
  const int id = blockIdx.x;
  if (id == 0 && tid == 0) *flag_ws = f32;  // for ln_kernel's output dtype

  if (id < 7488) {  // weight transposes
    int w, tt, R, C, bc, br;
    if (id < 2880)      { w = id / 576; tt = id % 576;  R = 768;  C = 768;  bc = (tt % 24) * 32; br = (tt / 24) * 32; }
    else if (id < 5184) { w = 5;        tt = id - 2880; R = 768;  C = 3072; bc = (tt % 96) * 32; br = (tt / 96) * 32; }
    else                { w = 6;        tt = id - 5184; R = 3072; C = 768;  bc = (tt % 24) * 32; br = (tt / 24) * 32; }
    const void* in = tp.src[w];
    u16* out = tp.dst[w];
    const int tx = tid & 31, ty = tid >> 5;
    for (int i = ty; i < 32; i += 8) {
      const size_t idx = (size_t)(br + i) * C + bc + tx;
      t[i][tx] = f32 ? f2b(((const float*)in)[idx]) : ((const u16*)in)[idx];
    }
    __syncthreads();
    for (int i = ty; i < 32; i += 8) out[(size_t)(bc + i) * R + br + tx] = t[tx][i];
  } else if (id < 12096) {  // x convert (4-wide)
    const int i = (id - 7488) * 256 + tid;
    if (i < B_ * S_ * D_ / 4) {
      if (f32) {
        const float4 f = ((const float4*)x)[i];
        ushort4 o;
        o.x = f2b(f.x); o.y = f2b(f.y); o.z = f2b(f.z); o.w = f2b(f.w);
        ((ushort4*)xb)[i] = o;
      } else {
        ((ushort4*)xb)[i] = ((const ushort4*)x)[i];
      }
    }
  } else if (id < 12672) {  // pe convert
    const int i = (id - 12096) * 256 + tid;
    if (i < (2 * S_ - 1) * D_ / 4) {
      if (f32) {
        const float4 f = ((const float4*)pe)[i];
        ushort4 o;
        o.x = f2b(f.x); o.y = f2b(f.y); o.z = f2b(f.z); o.w = f2b(f.w);
        ((ushort4*)peb)[i] = o;
      } else {
        ((ushort4*)peb)[i] = ((const ushort4*)pe)[i];
      }
    }
  } else {  // small tensors
    const int i = (id - 12672) * 256 + tid;
    if (i < 8448) {
      const void* s; u16* d; int off;
      if (i < 3072) { s = b1; d = b1c; off = i; }
      else {
        const int r = i - 3072, sg = r / 768; off = r - sg * 768;
        switch (sg) {
          case 0: s = ub;  d = ubc;  break;
          case 1: s = vb;  d = vbc;  break;
          case 2: s = b2;  d = b2c;  break;
          case 3: s = g1;  d = g1c;  break;
          case 4: s = be1; d = be1c; break;
          case 5: s = g2;  d = g2c;  break;
          default: s = be2; d = be2c; break;
        }
      }
      d[off] = f32 ? f2b(((const float*)s)[off]) : ((const u16*)s)[off];
    }
  }
}

// ---------------- GEMM v3: XOR-swizzled LDS + prefetch ----------------
// SWZ=1: XCD-chunked 1D swizzle (consecutive ids share an XCD chunk).
// SWZ=2: 2D supertile XCD swizzle — XCD c = d%8 owns a contiguous SX x SY
//   block subtile (SX=gx/2, SY=gy/4), so per-XCD L2 working set = A-sub +
//   B-sub (both ~2.25 MB at 128x64/K=768) < 4 MB L2. Requires gx%2==0, gy%4==0.
enum { F_BIAS = 1, F_RELU = 2, F_RES = 4 };

template <int TM, int TN, int WM, int WN, int FLAGS, int SWZ>
__global__ __launch_bounds__(256) void gemm3(
    const u16* __restrict__ A, const u16* __restrict__ Bt,
    u16* __restrict__ out0, const u16* __restrict__ bias0,
    const u16* __restrict__ res, int M, int N, int K) {
  constexpr int WAVES_M = TM / WM;
  constexpr int MT = WM / 16, NT = WN / 16;
  constexpr int NI = (TM + TN) / 64;
  static_assert((TM / WM) * (TN / WN) == 4, "4 waves");
  __shared__ u16 SM[2][(TM + TN) * 32];

  int bxx = blockIdx.x, byy = blockIdx.y;
  if (SWZ == 1) {
    const int gx = gridDim.x;
    const int nwg = gx * gridDim.y;
    if (!(nwg & 7)) {
      const int q = nwg >> 3;
      const int d = byy * gx + bxx;
      const int id = (d & 7) * q + (d >> 3);
      bxx = id % gx;
      byy = id / gx;
    }
  } else if (SWZ == 2) {
    const int gx = gridDim.x;
    const int SX = gx >> 1, SY = gridDim.y >> 2;
    const int d = byy * gx + bxx;
    const int c = d & 7, r = d >> 3;
    bxx = (c & 1) * SX + r % SX;
    byy = (c >> 1) * SY + r / SX;
  }
  const int m0 = byy * TM;
  const int n0 = bxx * TN;
  const int tid = threadIdx.x;
  const int wid = tid >> 6, lane = tid & 63;
  const int wm = (wid % WAVES_M) * WM, wn = (wid / WAVES_M) * WN;
  const int lm = lane & 15, quad = lane >> 4;

  floatx4 acc[MT][NT];
#pragma unroll
  for (int i = 0; i < MT; ++i)
#pragma unroll
    for (int j = 0; j < NT; ++j) acc[i][j] = (floatx4){0.f, 0.f, 0.f, 0.f};

  const u16* srcs[NI];
  int ldso[NI];
#pragma unroll
  for (int i = 0; i < NI; ++i) {
    const int j = wid + 4 * i;
    const int r = j * 16 + (lane >> 2);
    const int q = (lane & 3) ^ ((r >> 1) & 3);
    const u16* p;
    if (r < TM) {
      int ga = m0 + r;
      if (ga > M - 1) ga = M - 1;
      p = A + (size_t)ga * K + q * 8;
    } else {
      p = Bt + (size_t)(n0 + r - TM) * K + q * 8;
    }
    srcs[i] = p;
    ldso[i] = j * 512;
  }
  const int slot = (quad ^ ((lm >> 1) & 3)) * 8;
  int aoff[MT], boff[NT];
#pragma unroll
  for (int t = 0; t < MT; ++t) aoff[t] = (wm + t * 16 + lm) * 32 + slot;
#pragma unroll
  for (int t = 0; t < NT; ++t) boff[t] = (TM + wn + t * 16 + lm) * 32 + slot;

#pragma unroll
  for (int i = 0; i < NI; ++i) gload16(srcs[i], &SM[0][ldso[i]]);
  __syncthreads();

  int buf = 0;
  for (int k0 = 0; k0 < K; k0 += 32, buf ^= 1) {
    if (k0 + 32 < K) {
      const int koff = (k0 + 32);
#pragma unroll
      for (int i = 0; i < NI; ++i) gload16(srcs[i] + koff, &SM[buf ^ 1][ldso[i]]);
    }
    short8 af[MT], bf[NT];
#pragma unroll
    for (int t = 0; t < MT; ++t) af[t] = *(const short8*)(&SM[buf][aoff[t]]);
#pragma unroll
    for (int t = 0; t < NT; ++t) bf[t] = *(const short8*)(&SM[buf][boff[t]]);
#pragma unroll
    for (int tm = 0; tm < MT; ++tm)
#pragma unroll
      for (int tn = 0; tn < NT; ++tn)
        acc[tm][tn] = __builtin_amdgcn_mfma_f32_16x16x32_bf16(af[tm], bf[tn], acc[tm][tn], 0, 0, 0);
    __syncthreads();
  }

#pragma unroll
  for (int tm = 0; tm < MT; ++tm) {
#pragma unroll
    for (int tn = 0; tn < NT; ++tn) {
      const int gcol = n0 + wn + tn * 16 + lm;
#pragma unroll
      for (int r = 0; r < 4; ++r) {
        const int grow = m0 + wm + tm * 16 + quad * 4 + r;
        if (grow >= M) continue;
        float val = acc[tm][tn][r];
        if (FLAGS & F_BIAS) val += b2f(bias0[gcol]);
        if (FLAGS & F_RES) val += b2f(res[(size_t)grow * N + gcol]);
        if (FLAGS & F_RELU) val = fmaxf(val, 0.f);
        out0[(size_t)grow * N + gcol] = f2b(val);
      }
    }
  }
}

// ---------------- fused QKV (region epilogue + vt LDS-bounce) + r-proj ----------------
// v3: TN=64 (TM=128, WM=64, WN=32) + 2D supertile XCD swizzle for the QKV part:
// c = id%8 owns an 18x12 block subtile (A-sub 2.25 MB + B-sub 1.7 MB < 4 MB L2).
// Grid 1800: id<1728 -> QKV (36x48, N=2304); else -> r-proj (12x6, M=767).
__global__ __launch_bounds__(256) void gemm_qkv_rp(
    const u16* __restrict__ xb, const u16* __restrict__ wqkv,
    const u16* __restrict__ peb, const u16* __restrict__ wtr,
    u16* __restrict__ qu, u16* __restrict__ qv,
    u16* __restrict__ kbo, u16* __restrict__ vto, u16* __restrict__ rbo,
    const u16* __restrict__ ubias, const u16* __restrict__ vbias) {
  constexpr int TM = 128, TN = 64, WM = 64, WN = 32;
  constexpr int MT = 4, NT = 2, NI = 3;
  __shared__ u16 SM[2][(TM + TN) * 32];

  const int id = blockIdx.x;
  const int qkv = (id < 1728) ? 1 : 0;
  int bx, by, M;
  const u16 *A, *Bt;
  if (qkv) {
    // supertile: XCD c = id%8 gets subtile (c&1, c>>1) of 18x12 blocks
    const int c = id & 7, r = id >> 3;  // r in [0,216)
    bx = (c & 1) * 18 + r % 18;
    by = (c >> 1) * 12 + r / 18;
    M = B_ * S_; A = xb; Bt = wqkv;
  } else {
    const int t2 = id - 1728; bx = t2 % 12; by = t2 / 12; M = 767; A = peb; Bt = wtr;
  }
  const int K = 768;
  const int m0 = by * TM, n0 = bx * TN;
  const int tid = threadIdx.x;
  const int wid = tid >> 6, lane = tid & 63;
  const int wm = (wid & 1) * WM, wn = (wid >> 1) * WN;
  const int lm = lane & 15, quad = lane >> 4;

  floatx4 acc[MT][NT];
#pragma unroll
  for (int i = 0; i < MT; ++i)
#pragma unroll
    for (int j = 0; j < NT; ++j) acc[i][j] = (floatx4){0.f, 0.f, 0.f, 0.f};

  const u16* srcs[NI];
  int ldso[NI];
#pragma unroll
  for (int i = 0; i < NI; ++i) {
    const int j = wid + 4 * i;
    const int r = j * 16 + (lane >> 2);
    const int q = (lane & 3) ^ ((r >> 1) & 3);
    const u16* p;
    if (r < TM) {
      int ga = m0 + r;
      if (ga > M - 1) ga = M - 1;
      p = A + (size_t)ga * K + q * 8;
    } else {
      p = Bt + (size_t)(n0 + r - TM) * K + q * 8;
    }
    srcs[i] = p;
    ldso[i] = j * 512;
  }
  const int slot = (quad ^ ((lm >> 1) & 3)) * 8;
  int aoff[MT], boff[NT];
#pragma unroll
  for (int t = 0; t < MT; ++t) aoff[t] = (wm + t * 16 + lm) * 32 + slot;
#pragma unroll
  for (int t = 0; t < NT; ++t) boff[t] = (TM + wn + t * 16 + lm) * 32 + slot;

#pragma unroll
  for (int i = 0; i < NI; ++i) gload16(srcs[i], &SM[0][ldso[i]]);
  __syncthreads();

  int buf = 0;
  for (int k0 = 0; k0 < K; k0 += 32, buf ^= 1) {
    if (k0 + 32 < K) {
      const int koff = (k0 + 32);
#pragma unroll
      for (int i = 0; i < NI; ++i) gload16(srcs[i] + koff, &SM[buf ^ 1][ldso[i]]);
    }
    short8 af[MT], bf[NT];
#pragma unroll
    for (int t = 0; t < MT; ++t) af[t] = *(const short8*)(&SM[buf][aoff[t]]);
#pragma unroll
    for (int t = 0; t < NT; ++t) bf[t] = *(const short8*)(&SM[buf][boff[t]]);
#pragma unroll
    for (int tm = 0; tm < MT; ++tm)
#pragma unroll
      for (int tn = 0; tn < NT; ++tn)
        acc[tm][tn] = __builtin_amdgcn_mfma_f32_16x16x32_bf16(af[tm], bf[tn], acc[tm][tn], 0, 0, 0);
    __syncthreads();
  }

  if (!qkv) {  // r-proj plain store
#pragma unroll
    for (int tm = 0; tm < MT; ++tm)
#pragma unroll
      for (int tn = 0; tn < NT; ++tn) {
        const int gcol = n0 + wn + tn * 16 + lm;
#pragma unroll
        for (int r = 0; r < 4; ++r) {
          const int grow = m0 + wm + tm * 16 + quad * 4 + r;
          if (grow < M) rbo[(size_t)grow * 768 + gcol] = f2b(acc[tm][tn][r]);
        }
      }
    return;
  }
  // QKV epilogue; region is block-uniform (768 % 64 == 0)
  const int region = n0 / 768;
  if (region == 2) {
    // vt: coalesced store via per-wave LDS bounce (SM dead after last barrier)
    u16* wbuf = &SM[0][0] + wid * 1088;  // [64][17]
    const int bb = (m0 + wm) / S_;
    const int sbase = (m0 + wm) % S_;
    const int cl = lane >> 2, sc = (lane & 3) * 16;
#pragma unroll
    for (int tn = 0; tn < NT; ++tn) {
#pragma unroll
      for (int tm = 0; tm < MT; ++tm)
#pragma unroll
        for (int r = 0; r < 4; ++r)
          wbuf[(tm * 16 + quad * 4 + r) * 17 + lm] = f2b(acc[tm][tn][r]);
      short8 s0, s1;
#pragma unroll
      for (int j = 0; j < 8; ++j) s0[j] = (short)wbuf[(sc + j) * 17 + cl];
#pragma unroll
      for (int j = 0; j < 8; ++j) s1[j] = (short)wbuf[(sc + 8 + j) * 17 + cl];
      const int cglob = n0 - 1536 + wn + tn * 16 + cl;
      u16* dst = vto + ((size_t)(bb * D_ + cglob)) * S_ + sbase + sc;
      *(short8*)dst = s0;
      *(short8*)(dst + 8) = s1;
    }
    return;
  }
#pragma unroll
  for (int tm = 0; tm < MT; ++tm) {
#pragma unroll
    for (int tn = 0; tn < NT; ++tn) {
      const int gcol = n0 + wn + tn * 16 + lm;
      const int c = gcol - region * 768;
#pragma unroll
      for (int r = 0; r < 4; ++r) {
        const int grow = m0 + wm + tm * 16 + quad * 4 + r;
        const float val = acc[tm][tn][r];
        if (region == 0) {
          qu[(size_t)grow * 768 + c] = f2b(val + b2f(ubias[c]));
          qv[(size_t)grow * 768 + c] = f2b(val + b2f(vbias[c]));
        } else {
          kbo[(size_t)grow * 768 + c] = f2b(val);
        }
      }
    }
  }
}

// ---------------- attention v11: Eb eliminated (B_D scattered into scB) ----------------
// v10 was concurrency-starved: 24 waves/CU, all pipes <26% busy, ~85% idle.
// Occupancy was LDS-bound (scB 26.1K + Eb 27.1K = 53.4K -> 3 blocks/CU).
// v11: loop A scatters B_D scores DIRECTLY into scB at the reversed diagonal
// position c' = (row&15)+383-e (guard c'>=0; out-of-band hits the 24-col pad,
// never read). New barrier, then loop B RMWs A_C into the same cell.
// LDS: scB 26112 + rsum 128 = 26240 -> 4 blocks/CU = 2048 thr = 32 waves (max).
// launch_bounds(512,8): 64-VGPR cap (v10 used 40).
__global__ __launch_bounds__(512, 8) void attn_kernel(
    const u16* __restrict__ qu, const u16* __restrict__ qv,
    const u16* __restrict__ kb, const u16* __restrict__ vt,
    const u16* __restrict__ rb, u16* __restrict__ attn) {
  __shared__ u16 scB[32 * 408];   // B_D scatter, then +A_C (RMW), then P in place
  __shared__ float rsum[32];

  const int id = blockIdx.x;
  const int g = id >> 3;
  const int qt = g % 12;
  const int bh = (id & 7) + 8 * (g / 12);
  const int b = bh / H_, h = bh % H_;
  const int i0 = qt * 32;
  const int tid = threadIdx.x, wid = tid >> 6, lane = tid & 63;
  const int lm = lane & 15, quad = lane >> 4;

  const size_t qr0 = ((size_t)(b * S_ + i0 + lm)) * D_ + h * DH_;
  const size_t qr1 = qr0 + (size_t)16 * D_;

  // ---- Q fragments: time-shared registers (qv for loop A, qu for loop B) ----
  short8 q0a = *(const short8*)(qv + qr0 + quad * 8);
  short8 q0b = *(const short8*)(qv + qr0 + 32 + quad * 8);
  short8 q1a = *(const short8*)(qv + qr1 + quad * 8);
  short8 q1b = *(const short8*)(qv + qr1 + 32 + quad * 8);

  // pre-issue first kb unit load (j = wid): in flight during all of loop A
  const u16* kbase = kb + ((size_t)(b * S_ + lm)) * D_ + h * DH_ + quad * 8;
  short8 k0, k1;
  {
    const u16* p = kbase + (size_t)wid * 16 * D_;
    k0 = *(const short8*)p;
    k1 = *(const short8*)(p + 32);
  }

  // ---- loop A: rb units (B_D) -> scatter into scB at reversed positions ----
  short8 b0, b1;
  {
    // first unit m = wid (<8): t <= 479 < 766, no clamp needed
    const int t = i0 + 16 * wid + lm;
    const u16* p = rb + (size_t)t * D_ + h * DH_ + quad * 8;
    b0 = *(const short8*)p;
    b1 = *(const short8*)(p + 32);
  }
  for (int m = wid; m < 26; m += 8) {
    short8 n0 = b0, n1 = b1;
    const int mn = m + 8;
    if (mn < 26) {
      int t = i0 + 16 * mn + lm;
      if (t > 766) t = 766;
      const u16* pn = rb + (size_t)t * D_ + h * DH_ + quad * 8;
      n0 = *(const short8*)pn;
      n1 = *(const short8*)(pn + 32);
    }
    if (m <= 24) {
      floatx4 e = (floatx4){0.f, 0.f, 0.f, 0.f};
      e = __builtin_amdgcn_mfma_f32_16x16x32_bf16(q0a, b0, e, 0, 0, 0);
      e = __builtin_amdgcn_mfma_f32_16x16x32_bf16(q0b, b1, e, 0, 0, 0);
#pragma unroll
      for (int r = 0; r < 4; ++r) {
        const int row = quad * 4 + r;
        const int cp = row + 383 - (16 * m + lm);   // e-idx = 16m+lm
        if (cp >= 0) scB[row * 408 + cp] = f2b(e[r]);
      }
    }
    if (m >= 1) {
      floatx4 e = (floatx4){0.f, 0.f, 0.f, 0.f};
      e = __builtin_amdgcn_mfma_f32_16x16x32_bf16(q1a, b0, e, 0, 0, 0);
      e = __builtin_amdgcn_mfma_f32_16x16x32_bf16(q1b, b1, e, 0, 0, 0);
#pragma unroll
      for (int r = 0; r < 4; ++r) {
        const int row = quad * 4 + r;                // row&15 of (16+row)
        const int cp = row + 399 - 16 * m - lm;      // e-idx = 16(m-1)+lm
        if (cp >= 0) scB[(16 + row) * 408 + cp] = f2b(e[r]);
      }
    }
    b0 = n0;
    b1 = n1;
  }

  // ---- swap Q fragments: qu replaces qv in the same registers ----
  q0a = *(const short8*)(qu + qr0 + quad * 8);
  q0b = *(const short8*)(qu + qr0 + 32 + quad * 8);
  q1a = *(const short8*)(qu + qr1 + quad * 8);
  q1b = *(const short8*)(qu + qr1 + 32 + quad * 8);

  __syncthreads();  // barrier 0: all B_D scatter complete before A_C RMW

  // ---- loop B: kb units (A_C), RMW add into scB ----
  b0 = k0;
  b1 = k1;
  for (int j = wid; j < 24; j += 8) {
    short8 n0 = b0, n1 = b1;
    const int jn = j + 8;
    if (jn < 24) {
      const u16* pn = kbase + (size_t)jn * 16 * D_;
      n0 = *(const short8*)pn;
      n1 = *(const short8*)(pn + 32);
    }
    floatx4 e0 = (floatx4){0.f, 0.f, 0.f, 0.f};
    e0 = __builtin_amdgcn_mfma_f32_16x16x32_bf16(q0a, b0, e0, 0, 0, 0);
    e0 = __builtin_amdgcn_mfma_f32_16x16x32_bf16(q0b, b1, e0, 0, 0, 0);
    floatx4 e1 = (floatx4){0.f, 0.f, 0.f, 0.f};
    e1 = __builtin_amdgcn_mfma_f32_16x16x32_bf16(q1a, b0, e1, 0, 0, 0);
    e1 = __builtin_amdgcn_mfma_f32_16x16x32_bf16(q1b, b1, e1, 0, 0, 0);
    const int c = 16 * j + lm;
#pragma unroll
    for (int r = 0; r < 4; ++r) {
      const int o0 = (quad * 4 + r) * 408 + c;
      const int o1 = (16 + quad * 4 + r) * 408 + c;
      scB[o0] = f2b(e0[r] + b2f(scB[o0]));
      scB[o1] = f2b(e1[r] + b2f(scB[o1]));
    }
    b0 = n0;
    b1 = n1;
  }

  // ---- hoisted vt loads for phase 3 (independent of phases 1-2) ----
  const int rg = wid & 1, nt = wid >> 1;
  const size_t vbase = ((size_t)(b * D_ + h * DH_ + nt * 16 + lm)) * S_;
  short8 bv[12];
#pragma unroll
  for (int kk = 0; kk < 12; ++kk)
    bv[kk] = *(const short8*)(vt + vbase + kk * 32 + quad * 8);

  __syncthreads();  // barrier 1

  // ---- phase 2: single-pass softmax on pre-summed scores, vectorized ----
  {
    const int row = wid * 4 + quad;
    const int c0 = lm * 24;
    float lsum = 0.f;
#pragma unroll
    for (int t = 0; t < 3; ++t) {
      const short8 s8 = *(const short8*)(&scB[row * 408 + c0 + t * 8]);
      short8 p8;
#pragma unroll
      for (int j = 0; j < 8; ++j) {
        const float s = b2f((u16)s8[j]) * 0.125f;
        const float e = __expf(s);
        p8[j] = (short)f2b(e);
        lsum += e;
      }
      *(short8*)(&scB[row * 408 + c0 + t * 8]) = p8;
    }
#pragma unroll
    for (int m = 1; m < 16; m <<= 1) lsum += __shfl_xor(lsum, m);
    if (lm == 0) rsum[row] = lsum;
  }
  __syncthreads();  // barrier 2

  // ---- phase 3: PV from registers (bv) + LDS P ----
  {
    floatx4 oA = (floatx4){0.f, 0.f, 0.f, 0.f};
    floatx4 oB = (floatx4){0.f, 0.f, 0.f, 0.f};
    const int pbase = (rg * 16 + lm) * 408;
#pragma unroll
    for (int kk = 0; kk < 12; kk += 2) {
      const short8 afA = *(const short8*)(&scB[pbase + kk * 32 + quad * 8]);
      oA = __builtin_amdgcn_mfma_f32_16x16x32_bf16(afA, bv[kk], oA, 0, 0, 0);
      const short8 afB = *(const short8*)(&scB[pbase + (kk + 1) * 32 + quad * 8]);
      oB = __builtin_amdgcn_mfma_f32_16x16x32_bf16(afB, bv[kk + 1], oB, 0, 0, 0);
    }
#pragma unroll
    for (int r = 0; r < 4; ++r) {
      const int row = rg * 16 + quad * 4 + r;
      attn[((size_t)(b * S_ + i0 + row)) * D_ + h * DH_ + nt * 16 + lm] =
          f2b((oA[r] + oB[r]) / rsum[row]);
    }
  }
}

// ---------------- row layernorm ----------------
__global__ __launch_bounds__(256) void ln_kernel(const u16* __restrict__ y,
                                                 const u16* __restrict__ g,
                                                 const u16* __restrict__ bb,
                                                 void* __restrict__ outv,
                                                 const int* __restrict__ flag, int dual) {
  const int row = blockIdx.x * 4 + (threadIdx.x >> 6);
  const int lane = threadIdx.x & 63;
  const u16* yr = y + (size_t)row * D_;
  float vbuf[12], s = 0.f, s2 = 0.f;
#pragma unroll
  for (int i = 0; i < 12; ++i) {
    const float x = b2f(yr[lane + i * 64]);
    vbuf[i] = x;
    s += x;
    s2 += x * x;
  }
#pragma unroll
  for (int off = 32; off; off >>= 1) {
    s += __shfl_down(s, off);
    s2 += __shfl_down(s2, off);
  }
  s = __shfl(s, 0);
  s2 = __shfl(s2, 0);
  const float mean = s * (1.f / 768.f);
  const float var = s2 * (1.f / 768.f) - mean * mean;
  const float inv = rsqrtf(var + 1e-5f);
  const int f32out = dual && *flag;
#pragma unroll
  for (int i = 0; i < 12; ++i) {
    const int c = lane + i * 64;
    const float val = (vbuf[i] - mean) * inv * b2f(g[c]) + b2f(bb[c]);
    if (f32out) ((float*)outv)[(size_t)row * D_ + c] = val;
    else ((u16*)outv)[(size_t)row * D_ + c] = f2b(val);
  }
}

// ---------------- host ----------------
extern "C" void kernel_launch(void* const* d_in, const int* in_sizes, int n_in,
                              void* d_out, int out_size, void* d_ws, size_t ws_size,
                              hipStream_t stream) {
  const void* x    = d_in[0];
  const void* pe   = d_in[1];
  const void* Wq   = d_in[2];
  const void* Wk   = d_in[3];
  const void* Wv   = d_in[4];
  const void* Wr   = d_in[5];
  const void* ub   = d_in[6];
  const void* vb   = d_in[7];
  const void* Wo   = d_in[8];
  const void* ln1g = d_in[9];
  const void* ln1b = d_in[10];
  const void* ln2g = d_in[11];
  const void* ln2b = d_in[12];
  const void* W1   = d_in[13];
  const void* b1   = d_in[14];
  const void* W2   = d_in[15];
  const void* b2   = d_in[16];
  char* ws = (char*)d_ws;

  constexpr size_t O_W   = 0;
  constexpr size_t O_SM  = 15335424;
  constexpr size_t O_XB  = 15368192;
  constexpr size_t O_QU  = 24805376;
  constexpr size_t O_QV  = 34242560;
  constexpr size_t O_KB  = 43679744;
  constexpr size_t O_VT  = 53116928;
  constexpr size_t O_RB  = 62554112;
  constexpr size_t NEEDED = 63733760;

  if (ws_size < NEEDED) {
    fill_sentinel<<<(out_size + 255) / 256, 256, 0, stream>>>((u16*)d_out, out_size);
    return;
  }

  int* flag = (int*)(ws + O_SM);
  u16* ubc  = (u16*)(ws + O_SM + 128);
  u16* vbc  = (u16*)(ws + O_SM + 1664);
  u16* b1c  = (u16*)(ws + O_SM + 3200);
  u16* b2c  = (u16*)(ws + O_SM + 9344);
  u16* g1c  = (u16*)(ws + O_SM + 10880);
  u16* be1c = (u16*)(ws + O_SM + 12416);
  u16* g2c  = (u16*)(ws + O_SM + 13952);
  u16* be2c = (u16*)(ws + O_SM + 15488);

  u16* wtq = (u16*)(ws + O_W);   // wtq|wtk|wtv contiguous = fused QKV B
  u16* wtk = wtq + (size_t)D_ * D_;
  u16* wtv = wtk + (size_t)D_ * D_;
  u16* wtr = wtv + (size_t)D_ * D_;
  u16* wto = wtr + (size_t)D_ * D_;
  u16* wt1 = wto + (size_t)D_ * D_;
  u16* wt2 = wt1 + (size_t)D_ * FF_;

  u16* xb  = (u16*)(ws + O_XB);
  u16* quB = (u16*)(ws + O_QU);
  u16* qvB = (u16*)(ws + O_QV);
  u16* kbB = (u16*)(ws + O_KB);
  u16* vtB = (u16*)(ws + O_VT);
  u16* rbB = (u16*)(ws + O_RB);
  u16* peb = (u16*)d_out;          // pe lives in d_out until QKV+rproj completes
  u16* atB = (u16*)d_out;          // attn out overwrites peb afterwards (serial)
  u16* y1B = xb;
  u16* x1B = (u16*)(ws + O_VT);
  u16* ffB = xb;
  u16* y2B = x1B;

  TP tp;
  tp.src[0] = Wq; tp.src[1] = Wk; tp.src[2] = Wv; tp.src[3] = Wr; tp.src[4] = Wo;
  tp.src[5] = W1; tp.src[6] = W2;
  tp.dst[0] = wtq; tp.dst[1] = wtk; tp.dst[2] = wtv; tp.dst[3] = wtr; tp.dst[4] = wto;
  tp.dst[5] = wt1; tp.dst[6] = wt2;

  // 1) all conversions + transposes + dtype flag in one dispatch
  preamble_all<<<12705, 256, 0, stream>>>(tp, x, pe, b1, ub, vb, b2, ln1g, ln1b,
                                          ln2g, ln2b, xb, peb, b1c, ubc, vbc, b2c,
                                          g1c, be1c, g2c, be2c, flag);
  // 2) fused QKV (TN=64, supertile-swizzled: 1728 blocks) + r-proj (72)
  gemm_qkv_rp<<<1800, 256, 0, stream>>>(xb, wtq, peb, wtr, quB, qvB, kbB, vtB, rbB,
                                        ubc, vbc);
  // 3) attention -> d_out scratch
  attn_kernel<<<2304, 512, 0, stream>>>(quB, qvB, kbB, vtB, rbB, atB);
  // 4) Wo + residual — 64x64 tiles: grid (12,96)=1152 blocks
  gemm3<64, 64, 32, 32, F_RES, 1><<<dim3(12, 96), 256, 0, stream>>>(
      atB, wto, y1B, nullptr, xb, B_ * S_, D_, D_);
  ln_kernel<<<B_ * S_ / 4, 256, 0, stream>>>(y1B, g1c, be1c, x1B, flag, 0);
  // 5) FFN1 — 128x64 tiles + supertile swizzle: grid (48,48)=2304 blocks
  gemm3<128, 64, 64, 32, F_BIAS | F_RELU, 2><<<dim3(48, 48), 256, 0, stream>>>(
      x1B, wt1, ffB, b1c, nullptr, B_ * S_, FF_, D_);
  // 6) FFN2 — 64x64 tiles: grid (12,96)=1152 blocks
  gemm3<64, 64, 32, 32, F_BIAS | F_RES, 1><<<dim3(12, 96), 256, 0, stream>>>(
      ffB, wt2, y2B, b2c, x1B, B_ * S_, D_, FF_);
  ln_kernel<<<B_ * S_ / 4, 256, 0, stream>>>(y2B, g2c, be2c, d_out, flag, 1);
}

// Round 9
// 405.322 us; speedup vs baseline: 1.0756x; 1.0756x over previous
//
#include <hip/hip_runtime.h>

typedef unsigned short u16;
typedef __attribute__((ext_vector_type(8))) short short8;
typedef __attribute__((ext_vector_type(4))) float floatx4;

#define B_  16
#define S_  384
#define D_  768
#define H_  12
#define DH_ 64
#define FF_ 3072

__device__ __forceinline__ float b2f(u16 h) { return __uint_as_float(((unsigned)h) << 16); }
__device__ __forceinline__ u16 f2b(float f) {
  unsigned u = __float_as_uint(f);
  u += 0x7fffu + ((u >> 16) & 1u);
  return (u16)(u >> 16);
}

__device__ __forceinline__ void gload16(const u16* g, u16* l) {
  __builtin_amdgcn_global_load_lds(
      (const __attribute__((address_space(1))) unsigned int*)g,
      (__attribute__((address_space(3))) unsigned int*)l, 16, 0, 0);
}

__global__ __launch_bounds__(256) void fill_sentinel(u16* out, int n) {
  int i = blockIdx.x * 256 + threadIdx.x;
  if (i < n) out[i] = 0x42DE;  // bf16 111.0
}

// inline dtype detect: 256 u16 of x; fp32 low-halves hit exp>=0xC0 w.p. 0.25
__device__ __forceinline__ int detect_flag(const u16* x, int tid, int* sh) {
  const unsigned e = (x[tid] >> 7) & 0xFFu;
  const unsigned long long m = __ballot(e >= 0xC0u);
  if ((tid & 63) == 0) sh[tid >> 6] = (m != 0ull) ? 1 : 0;
  __syncthreads();
  return sh[0] | sh[1] | sh[2] | sh[3];
}

// ---------------- mega-preamble: transposes + converts + flag, ONE dispatch ----------------
struct TP { const void* src[7]; u16* dst[7]; };
__global__ __launch_bounds__(256) void preamble_all(
    TP tp, const void* x, const void* pe,
    const void* b1, const void* ub, const void* vb, const void* b2,
    const void* g1, const void* be1, const void* g2, const void* be2,
    u16* xb, u16* peb,
    u16* b1c, u16* ubc, u16* vbc, u16* b2c,
    u16* g1c, u16* be1c, u16* g2c, u16* be2c, int* flag_ws) {
  __shared__ u16 t[32][33];
  __shared__ int fl[4];
  const int tid = threadIdx.x;
  const int f32 = detect_flag((const u16*)x, tid, fl);
  const int id = blockIdx.x;
  if (id == 0 && tid == 0) *flag_ws = f32;  // for ln_kernel's output dtype

  if (id < 7488) {  // weight transposes
    int w, tt, R, C, bc, br;
    if (id < 2880)      { w = id / 576; tt = id % 576;  R = 768;  C = 768;  bc = (tt % 24) * 32; br = (tt / 24) * 32; }
    else if (id < 5184) { w = 5;        tt = id - 2880; R = 768;  C = 3072; bc = (tt % 96) * 32; br = (tt / 96) * 32; }
    else                { w = 6;        tt = id - 5184; R = 3072; C = 768;  bc = (tt % 24) * 32; br = (tt / 24) * 32; }
    const void* in = tp.src[w];
    u16* out = tp.dst[w];
    const int tx = tid & 31, ty = tid >> 5;
    for (int i = ty; i < 32; i += 8) {
      const size_t idx = (size_t)(br + i) * C + bc + tx;
      t[i][tx] = f32 ? f2b(((const float*)in)[idx]) : ((const u16*)in)[idx];
    }
    __syncthreads();
    for (int i = ty; i < 32; i += 8) out[(size_t)(bc + i) * R + br + tx] = t[tx][i];
  } else if (id < 12096) {  // x convert (4-wide)
    const int i = (id - 7488) * 256 + tid;
    if (i < B_ * S_ * D_ / 4) {
      if (f32) {
        const float4 f = ((const float4*)x)[i];
        ushort4 o;
        o.x = f2b(f.x); o.y = f2b(f.y); o.z = f2b(f.z); o.w = f2b(f.w);
        ((ushort4*)xb)[i] = o;
      } else {
        ((ushort4*)xb)[i] = ((const ushort4*)x)[i];
      }
    }
  } else if (id < 12672) {  // pe convert
    const int i = (id - 12096) * 256 + tid;
    if (i < (2 * S_ - 1) * D_ / 4) {
      if (f32) {
        const float4 f = ((const float4*)pe)[i];
        ushort4 o;
        o.x = f2b(f.x); o.y = f2b(f.y); o.z = f2b(f.z); o.w = f2b(f.w);
        ((ushort4*)peb)[i] = o;
      } else {
        ((ushort4*)peb)[i] = ((const ushort4*)pe)[i];
      }
    }
  } else {  // small tensors
    const int i = (id - 12672) * 256 + tid;
    if (i < 8448) {
      const void* s; u16* d; int off;
      if (i < 3072) { s = b1; d = b1c; off = i; }
      else {
        const int r = i - 3072, sg = r / 768; off = r - sg * 768;
        switch (sg) {
          case 0: s = ub;  d = ubc;  break;
          case 1: s = vb;  d = vbc;  break;
          case 2: s = b2;  d = b2c;  break;
          case 3: s = g1;  d = g1c;  break;
          case 4: s = be1; d = be1c; break;
          case 5: s = g2;  d = g2c;  break;
          default: s = be2; d = be2c; break;
        }
      }
      d[off] = f32 ? f2b(((const float*)s)[off]) : ((const u16*)s)[off];
    }
  }
}

// ---------------- GEMM v3: XOR-swizzled LDS + prefetch ----------------
// SWZ=1: XCD-chunked 1D swizzle (consecutive ids share an XCD chunk).
// SWZ=2: 2D supertile XCD swizzle — XCD c = d%8 owns a contiguous SX x SY
//   block subtile (SX=gx/2, SY=gy/4), so per-XCD L2 working set = A-sub +
//   B-sub (both ~2.25 MB at 128x64/K=768) < 4 MB L2. Requires gx%2==0, gy%4==0.
enum { F_BIAS = 1, F_RELU = 2, F_RES = 4 };

template <int TM, int TN, int WM, int WN, int FLAGS, int SWZ>
__global__ __launch_bounds__(256) void gemm3(
    const u16* __restrict__ A, const u16* __restrict__ Bt,
    u16* __restrict__ out0, const u16* __restrict__ bias0,
    const u16* __restrict__ res, int M, int N, int K) {
  constexpr int WAVES_M = TM / WM;
  constexpr int MT = WM / 16, NT = WN / 16;
  constexpr int NI = (TM + TN) / 64;
  static_assert((TM / WM) * (TN / WN) == 4, "4 waves");
  __shared__ u16 SM[2][(TM + TN) * 32];

  int bxx = blockIdx.x, byy = blockIdx.y;
  if (SWZ == 1) {
    const int gx = gridDim.x;
    const int nwg = gx * gridDim.y;
    if (!(nwg & 7)) {
      const int q = nwg >> 3;
      const int d = byy * gx + bxx;
      const int id = (d & 7) * q + (d >> 3);
      bxx = id % gx;
      byy = id / gx;
    }
  } else if (SWZ == 2) {
    const int gx = gridDim.x;
    const int SX = gx >> 1, SY = gridDim.y >> 2;
    const int d = byy * gx + bxx;
    const int c = d & 7, r = d >> 3;
    bxx = (c & 1) * SX + r % SX;
    byy = (c >> 1) * SY + r / SX;
  }
  const int m0 = byy * TM;
  const int n0 = bxx * TN;
  const int tid = threadIdx.x;
  const int wid = tid >> 6, lane = tid & 63;
  const int wm = (wid % WAVES_M) * WM, wn = (wid / WAVES_M) * WN;
  const int lm = lane & 15, quad = lane >> 4;

  floatx4 acc[MT][NT];
#pragma unroll
  for (int i = 0; i < MT; ++i)
#pragma unroll
    for (int j = 0; j < NT; ++j) acc[i][j] = (floatx4){0.f, 0.f, 0.f, 0.f};

  const u16* srcs[NI];
  int ldso[NI];
#pragma unroll
  for (int i = 0; i < NI; ++i) {
    const int j = wid + 4 * i;
    const int r = j * 16 + (lane >> 2);
    const int q = (lane & 3) ^ ((r >> 1) & 3);
    const u16* p;
    if (r < TM) {
      int ga = m0 + r;
      if (ga > M - 1) ga = M - 1;
      p = A + (size_t)ga * K + q * 8;
    } else {
      p = Bt + (size_t)(n0 + r - TM) * K + q * 8;
    }
    srcs[i] = p;
    ldso[i] = j * 512;
  }
  const int slot = (quad ^ ((lm >> 1) & 3)) * 8;
  int aoff[MT], boff[NT];
#pragma unroll
  for (int t = 0; t < MT; ++t) aoff[t] = (wm + t * 16 + lm) * 32 + slot;
#pragma unroll
  for (int t = 0; t < NT; ++t) boff[t] = (TM + wn + t * 16 + lm) * 32 + slot;

#pragma unroll
  for (int i = 0; i < NI; ++i) gload16(srcs[i], &SM[0][ldso[i]]);
  __syncthreads();

  int buf = 0;
  for (int k0 = 0; k0 < K; k0 += 32, buf ^= 1) {
    if (k0 + 32 < K) {
      const int koff = (k0 + 32);
#pragma unroll
      for (int i = 0; i < NI; ++i) gload16(srcs[i] + koff, &SM[buf ^ 1][ldso[i]]);
    }
    short8 af[MT], bf[NT];
#pragma unroll
    for (int t = 0; t < MT; ++t) af[t] = *(const short8*)(&SM[buf][aoff[t]]);
#pragma unroll
    for (int t = 0; t < NT; ++t) bf[t] = *(const short8*)(&SM[buf][boff[t]]);
#pragma unroll
    for (int tm = 0; tm < MT; ++tm)
#pragma unroll
      for (int tn = 0; tn < NT; ++tn)
        acc[tm][tn] = __builtin_amdgcn_mfma_f32_16x16x32_bf16(af[tm], bf[tn], acc[tm][tn], 0, 0, 0);
    __syncthreads();
  }

#pragma unroll
  for (int tm = 0; tm < MT; ++tm) {
#pragma unroll
    for (int tn = 0; tn < NT; ++tn) {
      const int gcol = n0 + wn + tn * 16 + lm;
#pragma unroll
      for (int r = 0; r < 4; ++r) {
        const int grow = m0 + wm + tm * 16 + quad * 4 + r;
        if (grow >= M) continue;
        float val = acc[tm][tn][r];
        if (FLAGS & F_BIAS) val += b2f(bias0[gcol]);
        if (FLAGS & F_RES) val += b2f(res[(size_t)grow * N + gcol]);
        if (FLAGS & F_RELU) val = fmaxf(val, 0.f);
        out0[(size_t)grow * N + gcol] = f2b(val);
      }
    }
  }
}

// ---------------- fused QKV (region epilogue + vt LDS-bounce) + r-proj ----------------
// v3: TN=64 (TM=128, WM=64, WN=32) + 2D supertile XCD swizzle for the QKV part:
// c = id%8 owns an 18x12 block subtile (A-sub 2.25 MB + B-sub 1.7 MB < 4 MB L2).
// Grid 1800: id<1728 -> QKV (36x48, N=2304); else -> r-proj (12x6, M=767).
__global__ __launch_bounds__(256) void gemm_qkv_rp(
    const u16* __restrict__ xb, const u16* __restrict__ wqkv,
    const u16* __restrict__ peb, const u16* __restrict__ wtr,
    u16* __restrict__ qu, u16* __restrict__ qv,
    u16* __restrict__ kbo, u16* __restrict__ vto, u16* __restrict__ rbo,
    const u16* __restrict__ ubias, const u16* __restrict__ vbias) {
  constexpr int TM = 128, TN = 64, WM = 64, WN = 32;
  constexpr int MT = 4, NT = 2, NI = 3;
  __shared__ u16 SM[2][(TM + TN) * 32];

  const int id = blockIdx.x;
  const int qkv = (id < 1728) ? 1 : 0;
  int bx, by, M;
  const u16 *A, *Bt;
  if (qkv) {
    // supertile: XCD c = id%8 gets subtile (c&1, c>>1) of 18x12 blocks
    const int c = id & 7, r = id >> 3;  // r in [0,216)
    bx = (c & 1) * 18 + r % 18;
    by = (c >> 1) * 12 + r / 18;
    M = B_ * S_; A = xb; Bt = wqkv;
  } else {
    const int t2 = id - 1728; bx = t2 % 12; by = t2 / 12; M = 767; A = peb; Bt = wtr;
  }
  const int K = 768;
  const int m0 = by * TM, n0 = bx * TN;
  const int tid = threadIdx.x;
  const int wid = tid >> 6, lane = tid & 63;
  const int wm = (wid & 1) * WM, wn = (wid >> 1) * WN;
  const int lm = lane & 15, quad = lane >> 4;

  floatx4 acc[MT][NT];
#pragma unroll
  for (int i = 0; i < MT; ++i)
#pragma unroll
    for (int j = 0; j < NT; ++j) acc[i][j] = (floatx4){0.f, 0.f, 0.f, 0.f};

  const u16* srcs[NI];
  int ldso[NI];
#pragma unroll
  for (int i = 0; i < NI; ++i) {
    const int j = wid + 4 * i;
    const int r = j * 16 + (lane >> 2);
    const int q = (lane & 3) ^ ((r >> 1) & 3);
    const u16* p;
    if (r < TM) {
      int ga = m0 + r;
      if (ga > M - 1) ga = M - 1;
      p = A + (size_t)ga * K + q * 8;
    } else {
      p = Bt + (size_t)(n0 + r - TM) * K + q * 8;
    }
    srcs[i] = p;
    ldso[i] = j * 512;
  }
  const int slot = (quad ^ ((lm >> 1) & 3)) * 8;
  int aoff[MT], boff[NT];
#pragma unroll
  for (int t = 0; t < MT; ++t) aoff[t] = (wm + t * 16 + lm) * 32 + slot;
#pragma unroll
  for (int t = 0; t < NT; ++t) boff[t] = (TM + wn + t * 16 + lm) * 32 + slot;

#pragma unroll
  for (int i = 0; i < NI; ++i) gload16(srcs[i], &SM[0][ldso[i]]);
  __syncthreads();

  int buf = 0;
  for (int k0 = 0; k0 < K; k0 += 32, buf ^= 1) {
    if (k0 + 32 < K) {
      const int koff = (k0 + 32);
#pragma unroll
      for (int i = 0; i < NI; ++i) gload16(srcs[i] + koff, &SM[buf ^ 1][ldso[i]]);
    }
    short8 af[MT], bf[NT];
#pragma unroll
    for (int t = 0; t < MT; ++t) af[t] = *(const short8*)(&SM[buf][aoff[t]]);
#pragma unroll
    for (int t = 0; t < NT; ++t) bf[t] = *(const short8*)(&SM[buf][boff[t]]);
#pragma unroll
    for (int tm = 0; tm < MT; ++tm)
#pragma unroll
      for (int tn = 0; tn < NT; ++tn)
        acc[tm][tn] = __builtin_amdgcn_mfma_f32_16x16x32_bf16(af[tm], bf[tn], acc[tm][tn], 0, 0, 0);
    __syncthreads();
  }

  if (!qkv) {  // r-proj plain store
#pragma unroll
    for (int tm = 0; tm < MT; ++tm)
#pragma unroll
      for (int tn = 0; tn < NT; ++tn) {
        const int gcol = n0 + wn + tn * 16 + lm;
#pragma unroll
        for (int r = 0; r < 4; ++r) {
          const int grow = m0 + wm + tm * 16 + quad * 4 + r;
          if (grow < M) rbo[(size_t)grow * 768 + gcol] = f2b(acc[tm][tn][r]);
        }
      }
    return;
  }
  // QKV epilogue; region is block-uniform (768 % 64 == 0)
  const int region = n0 / 768;
  if (region == 2) {
    // vt: coalesced store via per-wave LDS bounce (SM dead after last barrier)
    u16* wbuf = &SM[0][0] + wid * 1088;  // [64][17]
    const int bb = (m0 + wm) / S_;
    const int sbase = (m0 + wm) % S_;
    const int cl = lane >> 2, sc = (lane & 3) * 16;
#pragma unroll
    for (int tn = 0; tn < NT; ++tn) {
#pragma unroll
      for (int tm = 0; tm < MT; ++tm)
#pragma unroll
        for (int r = 0; r < 4; ++r)
          wbuf[(tm * 16 + quad * 4 + r) * 17 + lm] = f2b(acc[tm][tn][r]);
      short8 s0, s1;
#pragma unroll
      for (int j = 0; j < 8; ++j) s0[j] = (short)wbuf[(sc + j) * 17 + cl];
#pragma unroll
      for (int j = 0; j < 8; ++j) s1[j] = (short)wbuf[(sc + 8 + j) * 17 + cl];
      const int cglob = n0 - 1536 + wn + tn * 16 + cl;
      u16* dst = vto + ((size_t)(bb * D_ + cglob)) * S_ + sbase + sc;
      *(short8*)dst = s0;
      *(short8*)(dst + 8) = s1;
    }
    return;
  }
#pragma unroll
  for (int tm = 0; tm < MT; ++tm) {
#pragma unroll
    for (int tn = 0; tn < NT; ++tn) {
      const int gcol = n0 + wn + tn * 16 + lm;
      const int c = gcol - region * 768;
#pragma unroll
      for (int r = 0; r < 4; ++r) {
        const int grow = m0 + wm + tm * 16 + quad * 4 + r;
        const float val = acc[tm][tn][r];
        if (region == 0) {
          qu[(size_t)grow * 768 + c] = f2b(val + b2f(ubias[c]));
          qv[(size_t)grow * 768 + c] = f2b(val + b2f(vbias[c]));
        } else {
          kbo[(size_t)grow * 768 + c] = f2b(val);
        }
      }
    }
  }
}

// ---------------- attention v12: Eb-elim (v11) minus the spill sources ----------------
// v11 hit its occupancy target (4 blocks/CU) but (512,8) capped VGPR at 64 while
// the forced-live set (bv[12] hoist 48 + Q frags 16 + prefetch 24) exceeded it ->
// 62 KB/block scratch traffic (WRITE 9->142 MB), dur 75->102. v12 keeps the
// Eb-elimination and: (1) restores (512,6), the bound that produced clean
// 40-VGPR code in v9/v10 (8 waves/SIMD still reachable if usage <= 64);
// (2) drops the bv[12] hoist - vt is loaded inline in phase 3's unrolled loop,
// letting the scheduler hoist only what the register budget affords.
// LDS: scB 26112 + rsum 128 = 26240 -> 4 blocks/CU = 32 waves (HW max).
__global__ __launch_bounds__(512, 6) void attn_kernel(
    const u16* __restrict__ qu, const u16* __restrict__ qv,
    const u16* __restrict__ kb, const u16* __restrict__ vt,
    const u16* __restrict__ rb, u16* __restrict__ attn) {
  __shared__ u16 scB[32 * 408];   // B_D scatter, then +A_C (RMW), then P in place
  __shared__ float rsum[32];

  const int id = blockIdx.x;
  const int g = id >> 3;
  const int qt = g % 12;
  const int bh = (id & 7) + 8 * (g / 12);
  const int b = bh / H_, h = bh % H_;
  const int i0 = qt * 32;
  const int tid = threadIdx.x, wid = tid >> 6, lane = tid & 63;
  const int lm = lane & 15, quad = lane >> 4;

  const size_t qr0 = ((size_t)(b * S_ + i0 + lm)) * D_ + h * DH_;
  const size_t qr1 = qr0 + (size_t)16 * D_;

  // ---- Q fragments: time-shared registers (qv for loop A, qu for loop B) ----
  short8 q0a = *(const short8*)(qv + qr0 + quad * 8);
  short8 q0b = *(const short8*)(qv + qr0 + 32 + quad * 8);
  short8 q1a = *(const short8*)(qv + qr1 + quad * 8);
  short8 q1b = *(const short8*)(qv + qr1 + 32 + quad * 8);

  // pre-issue first kb unit load (j = wid): in flight during all of loop A
  const u16* kbase = kb + ((size_t)(b * S_ + lm)) * D_ + h * DH_ + quad * 8;
  short8 k0, k1;
  {
    const u16* p = kbase + (size_t)wid * 16 * D_;
    k0 = *(const short8*)p;
    k1 = *(const short8*)(p + 32);
  }

  // ---- loop A: rb units (B_D) -> scatter into scB at reversed positions ----
  short8 b0, b1;
  {
    // first unit m = wid (<8): t <= 479 < 766, no clamp needed
    const int t = i0 + 16 * wid + lm;
    const u16* p = rb + (size_t)t * D_ + h * DH_ + quad * 8;
    b0 = *(const short8*)p;
    b1 = *(const short8*)(p + 32);
  }
  for (int m = wid; m < 26; m += 8) {
    short8 n0 = b0, n1 = b1;
    const int mn = m + 8;
    if (mn < 26) {
      int t = i0 + 16 * mn + lm;
      if (t > 766) t = 766;
      const u16* pn = rb + (size_t)t * D_ + h * DH_ + quad * 8;
      n0 = *(const short8*)pn;
      n1 = *(const short8*)(pn + 32);
    }
    if (m <= 24) {
      floatx4 e = (floatx4){0.f, 0.f, 0.f, 0.f};
      e = __builtin_amdgcn_mfma_f32_16x16x32_bf16(q0a, b0, e, 0, 0, 0);
      e = __builtin_amdgcn_mfma_f32_16x16x32_bf16(q0b, b1, e, 0, 0, 0);
#pragma unroll
      for (int r = 0; r < 4; ++r) {
        const int row = quad * 4 + r;
        const int cp = row + 383 - (16 * m + lm);   // e-idx = 16m+lm
        if (cp >= 0) scB[row * 408 + cp] = f2b(e[r]);
      }
    }
    if (m >= 1) {
      floatx4 e = (floatx4){0.f, 0.f, 0.f, 0.f};
      e = __builtin_amdgcn_mfma_f32_16x16x32_bf16(q1a, b0, e, 0, 0, 0);
      e = __builtin_amdgcn_mfma_f32_16x16x32_bf16(q1b, b1, e, 0, 0, 0);
#pragma unroll
      for (int r = 0; r < 4; ++r) {
        const int row = quad * 4 + r;                // row&15 of (16+row)
        const int cp = row + 399 - 16 * m - lm;      // e-idx = 16(m-1)+lm
        if (cp >= 0) scB[(16 + row) * 408 + cp] = f2b(e[r]);
      }
    }
    b0 = n0;
    b1 = n1;
  }

  // ---- swap Q fragments: qu replaces qv in the same registers ----
  q0a = *(const short8*)(qu + qr0 + quad * 8);
  q0b = *(const short8*)(qu + qr0 + 32 + quad * 8);
  q1a = *(const short8*)(qu + qr1 + quad * 8);
  q1b = *(const short8*)(qu + qr1 + 32 + quad * 8);

  __syncthreads();  // barrier 0: all B_D scatter complete before A_C RMW

  // ---- loop B: kb units (A_C), RMW add into scB ----
  b0 = k0;
  b1 = k1;
  for (int j = wid; j < 24; j += 8) {
    short8 n0 = b0, n1 = b1;
    const int jn = j + 8;
    if (jn < 24) {
      const u16* pn = kbase + (size_t)jn * 16 * D_;
      n0 = *(const short8*)pn;
      n1 = *(const short8*)(pn + 32);
    }
    floatx4 e0 = (floatx4){0.f, 0.f, 0.f, 0.f};
    e0 = __builtin_amdgcn_mfma_f32_16x16x32_bf16(q0a, b0, e0, 0, 0, 0);
    e0 = __builtin_amdgcn_mfma_f32_16x16x32_bf16(q0b, b1, e0, 0, 0, 0);
    floatx4 e1 = (floatx4){0.f, 0.f, 0.f, 0.f};
    e1 = __builtin_amdgcn_mfma_f32_16x16x32_bf16(q1a, b0, e1, 0, 0, 0);
    e1 = __builtin_amdgcn_mfma_f32_16x16x32_bf16(q1b, b1, e1, 0, 0, 0);
    const int c = 16 * j + lm;
#pragma unroll
    for (int r = 0; r < 4; ++r) {
      const int o0 = (quad * 4 + r) * 408 + c;
      const int o1 = (16 + quad * 4 + r) * 408 + c;
      scB[o0] = f2b(e0[r] + b2f(scB[o0]));
      scB[o1] = f2b(e1[r] + b2f(scB[o1]));
    }
    b0 = n0;
    b1 = n1;
  }

  __syncthreads();  // barrier 1

  // ---- phase 2: single-pass softmax on pre-summed scores, vectorized ----
  {
    const int row = wid * 4 + quad;
    const int c0 = lm * 24;
    float lsum = 0.f;
#pragma unroll
    for (int t = 0; t < 3; ++t) {
      const short8 s8 = *(const short8*)(&scB[row * 408 + c0 + t * 8]);
      short8 p8;
#pragma unroll
      for (int j = 0; j < 8; ++j) {
        const float s = b2f((u16)s8[j]) * 0.125f;
        const float e = __expf(s);
        p8[j] = (short)f2b(e);
        lsum += e;
      }
      *(short8*)(&scB[row * 408 + c0 + t * 8]) = p8;
    }
#pragma unroll
    for (int m = 1; m < 16; m <<= 1) lsum += __shfl_xor(lsum, m);
    if (lm == 0) rsum[row] = lsum;
  }
  __syncthreads();  // barrier 2

  // ---- phase 3: PV, vt loaded inline (scheduler hoists within budget) ----
  {
    const int rg = wid & 1, nt = wid >> 1;
    const size_t vbase = ((size_t)(b * D_ + h * DH_ + nt * 16 + lm)) * S_;
    floatx4 oA = (floatx4){0.f, 0.f, 0.f, 0.f};
    floatx4 oB = (floatx4){0.f, 0.f, 0.f, 0.f};
    const int pbase = (rg * 16 + lm) * 408;
#pragma unroll
    for (int kk = 0; kk < 12; kk += 2) {
      const short8 bvA = *(const short8*)(vt + vbase + kk * 32 + quad * 8);
      const short8 afA = *(const short8*)(&scB[pbase + kk * 32 + quad * 8]);
      oA = __builtin_amdgcn_mfma_f32_16x16x32_bf16(afA, bvA, oA, 0, 0, 0);
      const short8 bvB = *(const short8*)(vt + vbase + (kk + 1) * 32 + quad * 8);
      const short8 afB = *(const short8*)(&scB[pbase + (kk + 1) * 32 + quad * 8]);
      oB = __builtin_amdgcn_mfma_f32_16x16x32_bf16(afB, bvB, oB, 0, 0, 0);
    }
#pragma unroll
    for (int r = 0; r < 4; ++r) {
      const int row = rg * 16 + quad * 4 + r;
      attn[((size_t)(b * S_ + i0 + row)) * D_ + h * DH_ + nt * 16 + lm] =
          f2b((oA[r] + oB[r]) / rsum[row]);
    }
  }
}

// ---------------- row layernorm ----------------
__global__ __launch_bounds__(256) void ln_kernel(const u16* __restrict__ y,
                                                 const u16* __restrict__ g,
                                                 const u16* __restrict__ bb,
                                                 void* __restrict__ outv,
                                                 const int* __restrict__ flag, int dual) {
  const int row = blockIdx.x * 4 + (threadIdx.x >> 6);
  const int lane = threadIdx.x & 63;
  const u16* yr = y + (size_t)row * D_;
  float vbuf[12], s = 0.f, s2 = 0.f;
#pragma unroll
  for (int i = 0; i < 12; ++i) {
    const float x = b2f(yr[lane + i * 64]);
    vbuf[i] = x;
    s += x;
    s2 += x * x;
  }
#pragma unroll
  for (int off = 32; off; off >>= 1) {
    s += __shfl_down(s, off);
    s2 += __shfl_down(s2, off);
  }
  s = __shfl(s, 0);
  s2 = __shfl(s2, 0);
  const float mean = s * (1.f / 768.f);
  const float var = s2 * (1.f / 768.f) - mean * mean;
  const float inv = rsqrtf(var + 1e-5f);
  const int f32out = dual && *flag;
#pragma unroll
  for (int i = 0; i < 12; ++i) {
    const int c = lane + i * 64;
    const float val = (vbuf[i] - mean) * inv * b2f(g[c]) + b2f(bb[c]);
    if (f32out) ((float*)outv)[(size_t)row * D_ + c] = val;
    else ((u16*)outv)[(size_t)row * D_ + c] = f2b(val);
  }
}

// ---------------- host ----------------
extern "C" void kernel_launch(void* const* d_in, const int* in_sizes, int n_in,
                              void* d_out, int out_size, void* d_ws, size_t ws_size,
                              hipStream_t stream) {
  const void* x    = d_in[0];
  const void* pe   = d_in[1];
  const void* Wq   = d_in[2];
  const void* Wk   = d_in[3];
  const void* Wv   = d_in[4];
  const void* Wr   = d_in[5];
  const void* ub   = d_in[6];
  const void* vb   = d_in[7];
  const void* Wo   = d_in[8];
  const void* ln1g = d_in[9];
  const void* ln1b = d_in[10];
  const void* ln2g = d_in[11];
  const void* ln2b = d_in[12];
  const void* W1   = d_in[13];
  const void* b1   = d_in[14];
  const void* W2   = d_in[15];
  const void* b2   = d_in[16];
  char* ws = (char*)d_ws;

  constexpr size_t O_W   = 0;
  constexpr size_t O_SM  = 15335424;
  constexpr size_t O_XB  = 15368192;
  constexpr size_t O_QU  = 24805376;
  constexpr size_t O_QV  = 34242560;
  constexpr size_t O_KB  = 43679744;
  constexpr size_t O_VT  = 53116928;
  constexpr size_t O_RB  = 62554112;
  constexpr size_t NEEDED = 63733760;

  if (ws_size < NEEDED) {
    fill_sentinel<<<(out_size + 255) / 256, 256, 0, stream>>>((u16*)d_out, out_size);
    return;
  }

  int* flag = (int*)(ws + O_SM);
  u16* ubc  = (u16*)(ws + O_SM + 128);
  u16* vbc  = (u16*)(ws + O_SM + 1664);
  u16* b1c  = (u16*)(ws + O_SM + 3200);
  u16* b2c  = (u16*)(ws + O_SM + 9344);
  u16* g1c  = (u16*)(ws + O_SM + 10880);
  u16* be1c = (u16*)(ws + O_SM + 12416);
  u16* g2c  = (u16*)(ws + O_SM + 13952);
  u16* be2c = (u16*)(ws + O_SM + 15488);

  u16* wtq = (u16*)(ws + O_W);   // wtq|wtk|wtv contiguous = fused QKV B
  u16* wtk = wtq + (size_t)D_ * D_;
  u16* wtv = wtk + (size_t)D_ * D_;
  u16* wtr = wtv + (size_t)D_ * D_;
  u16* wto = wtr + (size_t)D_ * D_;
  u16* wt1 = wto + (size_t)D_ * D_;
  u16* wt2 = wt1 + (size_t)D_ * FF_;

  u16* xb  = (u16*)(ws + O_XB);
  u16* quB = (u16*)(ws + O_QU);
  u16* qvB = (u16*)(ws + O_QV);
  u16* kbB = (u16*)(ws + O_KB);
  u16* vtB = (u16*)(ws + O_VT);
  u16* rbB = (u16*)(ws + O_RB);
  u16* peb = (u16*)d_out;          // pe lives in d_out until QKV+rproj completes
  u16* atB = (u16*)d_out;          // attn out overwrites peb afterwards (serial)
  u16* y1B = xb;
  u16* x1B = (u16*)(ws + O_VT);
  u16* ffB = xb;
  u16* y2B = x1B;

  TP tp;
  tp.src[0] = Wq; tp.src[1] = Wk; tp.src[2] = Wv; tp.src[3] = Wr; tp.src[4] = Wo;
  tp.src[5] = W1; tp.src[6] = W2;
  tp.dst[0] = wtq; tp.dst[1] = wtk; tp.dst[2] = wtv; tp.dst[3] = wtr; tp.dst[4] = wto;
  tp.dst[5] = wt1; tp.dst[6] = wt2;

  // 1) all conversions + transposes + dtype flag in one dispatch
  preamble_all<<<12705, 256, 0, stream>>>(tp, x, pe, b1, ub, vb, b2, ln1g, ln1b,
                                          ln2g, ln2b, xb, peb, b1c, ubc, vbc, b2c,
                                          g1c, be1c, g2c, be2c, flag);
  // 2) fused QKV (TN=64, supertile-swizzled: 1728 blocks) + r-proj (72)
  gemm_qkv_rp<<<1800, 256, 0, stream>>>(xb, wtq, peb, wtr, quB, qvB, kbB, vtB, rbB,
                                        ubc, vbc);
  // 3) attention -> d_out scratch
  attn_kernel<<<2304, 512, 0, stream>>>(quB, qvB, kbB, vtB, rbB, atB);
  // 4) Wo + residual — 64x64 tiles: grid (12,96)=1152 blocks
  gemm3<64, 64, 32, 32, F_RES, 1><<<dim3(12, 96), 256, 0, stream>>>(
      atB, wto, y1B, nullptr, xb, B_ * S_, D_, D_);
  ln_kernel<<<B_ * S_ / 4, 256, 0, stream>>>(y1B, g1c, be1c, x1B, flag, 0);
  // 5) FFN1 — 128x64 tiles + supertile swizzle: grid (48,48)=2304 blocks
  gemm3<128, 64, 64, 32, F_BIAS | F_RELU, 2><<<dim3(48, 48), 256, 0, stream>>>(
      x1B, wt1, ffB, b1c, nullptr, B_ * S_, FF_, D_);
  // 6) FFN2 — 64x64 tiles: grid (12,96)=1152 blocks
  gemm3<64, 64, 32, 32, F_BIAS | F_RES, 1><<<dim3(12, 96), 256, 0, stream>>>(
      ffB, wt2, y2B, b2c, x1B, B_ * S_, D_, FF_);
  ln_kernel<<<B_ * S_ / 4, 256, 0, stream>>>(y2B, g2c, be2c, d_out, flag, 1);
}

// Round 11
// 403.819 us; speedup vs baseline: 1.0796x; 1.0037x over previous
//
#include <hip/hip_runtime.h>

typedef unsigned short u16;
typedef __attribute__((ext_vector_type(8))) short short8;
typedef __attribute__((ext_vector_type(4))) float floatx4;

#define B_  16
#define S_  384
#define D_  768
#define H_  12
#define DH_ 64
#define FF_ 3072

__device__ __forceinline__ float b2f(u16 h) { return __uint_as_float(((unsigned)h) << 16); }
__device__ __forceinline__ u16 f2b(float f) {
  unsigned u = __float_as_uint(f);
  u += 0x7fffu + ((u >> 16) & 1u);
  return (u16)(u >> 16);
}

__device__ __forceinline__ void gload16(const u16* g, u16* l) {
  __builtin_amdgcn_global_load_lds(
      (const __attribute__((address_space(1))) unsigned int*)g,
      (__attribute__((address_space(3))) unsigned int*)l, 16, 0, 0);
}

__global__ __launch_bounds__(256) void fill_sentinel(u16* out, int n) {
  int i = blockIdx.x * 256 + threadIdx.x;
  if (i < n) out[i] = 0x42DE;  // bf16 111.0
}

// inline dtype detect: 256 u16 of x; fp32 low-halves hit exp>=0xC0 w.p. 0.25
__device__ __forceinline__ int detect_flag(const u16* x, int tid, int* sh) {
  const unsigned e = (x[tid] >> 7) & 0xFFu;
  const unsigned long long m = __ballot(e >= 0xC0u);
  if ((tid & 63) == 0) sh[tid >> 6] = (m != 0ull) ? 1 : 0;
  __syncthreads();
  return sh[0] | sh[1] | sh[2] | sh[3];
}

// ---------------- mega-preamble: transposes + converts + flag, ONE dispatch ----------------
struct TP { const void* src[7]; u16* dst[7]; };
__global__ __launch_bounds__(256) void preamble_all(
    TP tp, const void* x, const void* pe,
    const void* b1, const void* ub, const void* vb, const void* b2,
    const void* g1, const void* be1, const void* g2, const void* be2,
    u16* xb, u16* peb,
    u16* b1c, u16* ubc, u16* vbc, u16* b2c,
    u16* g1c, u16* be1c, u16* g2c, u16* be2c, int* flag_ws) {
  __shared__ u16 t[32][33];
  __shared__ int fl[4];
  const int tid = threadIdx.x;
  const int f32 = detect_flag((const u16*)x, tid, fl);
  const int id = blockIdx.x;
  if (id == 0 && tid == 0) *flag_ws = f32;  // for ln_kernel's output dtype

  if (id < 7488) {  // weight transposes
    int w, tt, R, C, bc, br;
    if (id < 2880)      { w = id / 576; tt = id % 576;  R = 768;  C = 768;  bc = (tt % 24) * 32; br = (tt / 24) * 32; }
    else if (id < 5184) { w = 5;        tt = id - 2880; R = 768;  C = 3072; bc = (tt % 96) * 32; br = (tt / 96) * 32; }
    else                { w = 6;        tt = id - 5184; R = 3072; C = 768;  bc = (tt % 24) * 32; br = (tt / 24) * 32; }
    const void* in = tp.src[w];
    u16* out = tp.dst[w];
    const int tx = tid & 31, ty = tid >> 5;
    for (int i = ty; i < 32; i += 8) {
      const size_t idx = (size_t)(br + i) * C + bc + tx;
      t[i][tx] = f32 ? f2b(((const float*)in)[idx]) : ((const u16*)in)[idx];
    }
    __syncthreads();
    for (int i = ty; i < 32; i += 8) out[(size_t)(bc + i) * R + br + tx] = t[tx][i];
  } else if (id < 12096) {  // x convert (4-wide)
    const int i = (id - 7488) * 256 + tid;
    if (i < B_ * S_ * D_ / 4) {
      if (f32) {
        const float4 f = ((const float4*)x)[i];
        ushort4 o;
        o.x = f2b(f.x); o.y = f2b(f.y); o.z = f2b(f.z); o.w = f2b(f.w);
        ((ushort4*)xb)[i] = o;
      } else {
        ((ushort4*)xb)[i] = ((const ushort4*)x)[i];
      }
    }
  } else if (id < 12672) {  // pe convert
    const int i = (id - 12096) * 256 + tid;
    if (i < (2 * S_ - 1) * D_ / 4) {
      if (f32) {
        const float4 f = ((const float4*)pe)[i];
        ushort4 o;
        o.x = f2b(f.x); o.y = f2b(f.y); o.z = f2b(f.z); o.w = f2b(f.w);
        ((ushort4*)peb)[i] = o;
      } else {
        ((ushort4*)peb)[i] = ((const ushort4*)pe)[i];
      }
    }
  } else {  // small tensors
    const int i = (id - 12672) * 256 + tid;
    if (i < 8448) {
      const void* s; u16* d; int off;
      if (i < 3072) { s = b1; d = b1c; off = i; }
      else {
        const int r = i - 3072, sg = r / 768; off = r - sg * 768;
        switch (sg) {
          case 0: s = ub;  d = ubc;  break;
          case 1: s = vb;  d = vbc;  break;
          case 2: s = b2;  d = b2c;  break;
          case 3: s = g1;  d = g1c;  break;
          case 4: s = be1; d = be1c; break;
          case 5: s = g2;  d = g2c;  break;
          default: s = be2; d = be2c; break;
        }
      }
      d[off] = f32 ? f2b(((const float*)s)[off]) : ((const u16*)s)[off];
    }
  }
}

// ---------------- GEMM v3: XOR-swizzled LDS + prefetch ----------------
// SWZ=1: XCD-chunked 1D swizzle (consecutive ids share an XCD chunk).
// SWZ=2: 2D supertile XCD swizzle — XCD c = d%8 owns a contiguous SX x SY
//   block subtile (SX=gx/2, SY=gy/4), so per-XCD L2 working set = A-sub +
//   B-sub (both ~2.25 MB at 128x64/K=768) < 4 MB L2. Requires gx%2==0, gy%4==0.
enum { F_BIAS = 1, F_RELU = 2, F_RES = 4 };

template <int TM, int TN, int WM, int WN, int FLAGS, int SWZ>
__global__ __launch_bounds__(256) void gemm3(
    const u16* __restrict__ A, const u16* __restrict__ Bt,
    u16* __restrict__ out0, const u16* __restrict__ bias0,
    const u16* __restrict__ res, int M, int N, int K) {
  constexpr int WAVES_M = TM / WM;
  constexpr int MT = WM / 16, NT = WN / 16;
  constexpr int NI = (TM + TN) / 64;
  static_assert((TM / WM) * (TN / WN) == 4, "4 waves");
  __shared__ u16 SM[2][(TM + TN) * 32];

  int bxx = blockIdx.x, byy = blockIdx.y;
  if (SWZ == 1) {
    const int gx = gridDim.x;
    const int nwg = gx * gridDim.y;
    if (!(nwg & 7)) {
      const int q = nwg >> 3;
      const int d = byy * gx + bxx;
      const int id = (d & 7) * q + (d >> 3);
      bxx = id % gx;
      byy = id / gx;
    }
  } else if (SWZ == 2) {
    const int gx = gridDim.x;
    const int SX = gx >> 1, SY = gridDim.y >> 2;
    const int d = byy * gx + bxx;
    const int c = d & 7, r = d >> 3;
    bxx = (c & 1) * SX + r % SX;
    byy = (c >> 1) * SY + r / SX;
  }
  const int m0 = byy * TM;
  const int n0 = bxx * TN;
  const int tid = threadIdx.x;
  const int wid = tid >> 6, lane = tid & 63;
  const int wm = (wid % WAVES_M) * WM, wn = (wid / WAVES_M) * WN;
  const int lm = lane & 15, quad = lane >> 4;

  floatx4 acc[MT][NT];
#pragma unroll
  for (int i = 0; i < MT; ++i)
#pragma unroll
    for (int j = 0; j < NT; ++j) acc[i][j] = (floatx4){0.f, 0.f, 0.f, 0.f};

  const u16* srcs[NI];
  int ldso[NI];
#pragma unroll
  for (int i = 0; i < NI; ++i) {
    const int j = wid + 4 * i;
    const int r = j * 16 + (lane >> 2);
    const int q = (lane & 3) ^ ((r >> 1) & 3);
    const u16* p;
    if (r < TM) {
      int ga = m0 + r;
      if (ga > M - 1) ga = M - 1;
      p = A + (size_t)ga * K + q * 8;
    } else {
      p = Bt + (size_t)(n0 + r - TM) * K + q * 8;
    }
    srcs[i] = p;
    ldso[i] = j * 512;
  }
  const int slot = (quad ^ ((lm >> 1) & 3)) * 8;
  int aoff[MT], boff[NT];
#pragma unroll
  for (int t = 0; t < MT; ++t) aoff[t] = (wm + t * 16 + lm) * 32 + slot;
#pragma unroll
  for (int t = 0; t < NT; ++t) boff[t] = (TM + wn + t * 16 + lm) * 32 + slot;

#pragma unroll
  for (int i = 0; i < NI; ++i) gload16(srcs[i], &SM[0][ldso[i]]);
  __syncthreads();

  int buf = 0;
  for (int k0 = 0; k0 < K; k0 += 32, buf ^= 1) {
    if (k0 + 32 < K) {
      const int koff = (k0 + 32);
#pragma unroll
      for (int i = 0; i < NI; ++i) gload16(srcs[i] + koff, &SM[buf ^ 1][ldso[i]]);
    }
    short8 af[MT], bf[NT];
#pragma unroll
    for (int t = 0; t < MT; ++t) af[t] = *(const short8*)(&SM[buf][aoff[t]]);
#pragma unroll
    for (int t = 0; t < NT; ++t) bf[t] = *(const short8*)(&SM[buf][boff[t]]);
#pragma unroll
    for (int tm = 0; tm < MT; ++tm)
#pragma unroll
      for (int tn = 0; tn < NT; ++tn)
        acc[tm][tn] = __builtin_amdgcn_mfma_f32_16x16x32_bf16(af[tm], bf[tn], acc[tm][tn], 0, 0, 0);
    __syncthreads();
  }

#pragma unroll
  for (int tm = 0; tm < MT; ++tm) {
#pragma unroll
    for (int tn = 0; tn < NT; ++tn) {
      const int gcol = n0 + wn + tn * 16 + lm;
#pragma unroll
      for (int r = 0; r < 4; ++r) {
        const int grow = m0 + wm + tm * 16 + quad * 4 + r;
        if (grow >= M) continue;
        float val = acc[tm][tn][r];
        if (FLAGS & F_BIAS) val += b2f(bias0[gcol]);
        if (FLAGS & F_RES) val += b2f(res[(size_t)grow * N + gcol]);
        if (FLAGS & F_RELU) val = fmaxf(val, 0.f);
        out0[(size_t)grow * N + gcol] = f2b(val);
      }
    }
  }
}

// ---------------- fused QKV (region epilogue + vt LDS-bounce) + r-proj ----------------
// v3: TN=64 (TM=128, WM=64, WN=32) + 2D supertile XCD swizzle for the QKV part:
// c = id%8 owns an 18x12 block subtile (A-sub 2.25 MB + B-sub 1.7 MB < 4 MB L2).
// Grid 1800: id<1728 -> QKV (36x48, N=2304); else -> r-proj (12x6, M=767).
__global__ __launch_bounds__(256) void gemm_qkv_rp(
    const u16* __restrict__ xb, const u16* __restrict__ wqkv,
    const u16* __restrict__ peb, const u16* __restrict__ wtr,
    u16* __restrict__ qu, u16* __restrict__ qv,
    u16* __restrict__ kbo, u16* __restrict__ vto, u16* __restrict__ rbo,
    const u16* __restrict__ ubias, const u16* __restrict__ vbias) {
  constexpr int TM = 128, TN = 64, WM = 64, WN = 32;
  constexpr int MT = 4, NT = 2, NI = 3;
  __shared__ u16 SM[2][(TM + TN) * 32];

  const int id = blockIdx.x;
  const int qkv = (id < 1728) ? 1 : 0;
  int bx, by, M;
  const u16 *A, *Bt;
  if (qkv) {
    // supertile: XCD c = id%8 gets subtile (c&1, c>>1) of 18x12 blocks
    const int c = id & 7, r = id >> 3;  // r in [0,216)
    bx = (c & 1) * 18 + r % 18;
    by = (c >> 1) * 12 + r / 18;
    M = B_ * S_; A = xb; Bt = wqkv;
  } else {
    const int t2 = id - 1728; bx = t2 % 12; by = t2 / 12; M = 767; A = peb; Bt = wtr;
  }
  const int K = 768;
  const int m0 = by * TM, n0 = bx * TN;
  const int tid = threadIdx.x;
  const int wid = tid >> 6, lane = tid & 63;
  const int wm = (wid & 1) * WM, wn = (wid >> 1) * WN;
  const int lm = lane & 15, quad = lane >> 4;

  floatx4 acc[MT][NT];
#pragma unroll
  for (int i = 0; i < MT; ++i)
#pragma unroll
    for (int j = 0; j < NT; ++j) acc[i][j] = (floatx4){0.f, 0.f, 0.f, 0.f};

  const u16* srcs[NI];
  int ldso[NI];
#pragma unroll
  for (int i = 0; i < NI; ++i) {
    const int j = wid + 4 * i;
    const int r = j * 16 + (lane >> 2);
    const int q = (lane & 3) ^ ((r >> 1) & 3);
    const u16* p;
    if (r < TM) {
      int ga = m0 + r;
      if (ga > M - 1) ga = M - 1;
      p = A + (size_t)ga * K + q * 8;
    } else {
      p = Bt + (size_t)(n0 + r - TM) * K + q * 8;
    }
    srcs[i] = p;
    ldso[i] = j * 512;
  }
  const int slot = (quad ^ ((lm >> 1) & 3)) * 8;
  int aoff[MT], boff[NT];
#pragma unroll
  for (int t = 0; t < MT; ++t) aoff[t] = (wm + t * 16 + lm) * 32 + slot;
#pragma unroll
  for (int t = 0; t < NT; ++t) boff[t] = (TM + wn + t * 16 + lm) * 32 + slot;

#pragma unroll
  for (int i = 0; i < NI; ++i) gload16(srcs[i], &SM[0][ldso[i]]);
  __syncthreads();

  int buf = 0;
  for (int k0 = 0; k0 < K; k0 += 32, buf ^= 1) {
    if (k0 + 32 < K) {
      const int koff = (k0 + 32);
#pragma unroll
      for (int i = 0; i < NI; ++i) gload16(srcs[i] + koff, &SM[buf ^ 1][ldso[i]]);
    }
    short8 af[MT], bf[NT];
#pragma unroll
    for (int t = 0; t < MT; ++t) af[t] = *(const short8*)(&SM[buf][aoff[t]]);
#pragma unroll
    for (int t = 0; t < NT; ++t) bf[t] = *(const short8*)(&SM[buf][boff[t]]);
#pragma unroll
    for (int tm = 0; tm < MT; ++tm)
#pragma unroll
      for (int tn = 0; tn < NT; ++tn)
        acc[tm][tn] = __builtin_amdgcn_mfma_f32_16x16x32_bf16(af[tm], bf[tn], acc[tm][tn], 0, 0, 0);
    __syncthreads();
  }

  if (!qkv) {  // r-proj plain store
#pragma unroll
    for (int tm = 0; tm < MT; ++tm)
#pragma unroll
      for (int tn = 0; tn < NT; ++tn) {
        const int gcol = n0 + wn + tn * 16 + lm;
#pragma unroll
        for (int r = 0; r < 4; ++r) {
          const int grow = m0 + wm + tm * 16 + quad * 4 + r;
          if (grow < M) rbo[(size_t)grow * 768 + gcol] = f2b(acc[tm][tn][r]);
        }
      }
    return;
  }
  // QKV epilogue; region is block-uniform (768 % 64 == 0)
  const int region = n0 / 768;
  if (region == 2) {
    // vt: coalesced store via per-wave LDS bounce (SM dead after last barrier)
    u16* wbuf = &SM[0][0] + wid * 1088;  // [64][17]
    const int bb = (m0 + wm) / S_;
    const int sbase = (m0 + wm) % S_;
    const int cl = lane >> 2, sc = (lane & 3) * 16;
#pragma unroll
    for (int tn = 0; tn < NT; ++tn) {
#pragma unroll
      for (int tm = 0; tm < MT; ++tm)
#pragma unroll
        for (int r = 0; r < 4; ++r)
          wbuf[(tm * 16 + quad * 4 + r) * 17 + lm] = f2b(acc[tm][tn][r]);
      short8 s0, s1;
#pragma unroll
      for (int j = 0; j < 8; ++j) s0[j] = (short)wbuf[(sc + j) * 17 + cl];
#pragma unroll
      for (int j = 0; j < 8; ++j) s1[j] = (short)wbuf[(sc + 8 + j) * 17 + cl];
      const int cglob = n0 - 1536 + wn + tn * 16 + cl;
      u16* dst = vto + ((size_t)(bb * D_ + cglob)) * S_ + sbase + sc;
      *(short8*)dst = s0;
      *(short8*)(dst + 8) = s1;
    }
    return;
  }
#pragma unroll
  for (int tm = 0; tm < MT; ++tm) {
#pragma unroll
    for (int tn = 0; tn < NT; ++tn) {
      const int gcol = n0 + wn + tn * 16 + lm;
      const int c = gcol - region * 768;
#pragma unroll
      for (int r = 0; r < 4; ++r) {
        const int grow = m0 + wm + tm * 16 + quad * 4 + r;
        const float val = acc[tm][tn][r];
        if (region == 0) {
          qu[(size_t)grow * 768 + c] = f2b(val + b2f(ubias[c]));
          qv[(size_t)grow * 768 + c] = f2b(val + b2f(vbias[c]));
        } else {
          kbo[(size_t)grow * 768 + c] = f2b(val);
        }
      }
    }
  }
}

// ---------------- attention v14: v12 + softmax fused into loop B ----------------
// v13's inline-asm cvt_pk NaN'd (guide T12/m240 warns against hand-writing it) —
// reverted. v14 keeps v12's verified structure and deletes the phase-2 LDS
// round-trip: loop B already holds the summed score in registers, so it applies
// *0.125 -> exp -> f2b directly and writes P (same cells -> PV unchanged),
// accumulating per-row partial sums in psum[8] (compile-time indexed). Row sums
// finish via shfl_xor over the 16-lane quad group (rows are quad-owned) ->
// rp[32][8] partials -> 32-thread mini-reduce between barriers 1 and 2.
// No new barrier; one less bf16 rounding of the score.
// LDS: scB 26112 + rp 1024 + rsum 128 = 27264 B (>= 4 blocks/CU, above 32-wave cap).
__global__ __launch_bounds__(512, 6) void attn_kernel(
    const u16* __restrict__ qu, const u16* __restrict__ qv,
    const u16* __restrict__ kb, const u16* __restrict__ vt,
    const u16* __restrict__ rb, u16* __restrict__ attn) {
  __shared__ u16 scB[32 * 408];   // B_D scatter, then P (bf16) in place
  __shared__ float rp[32][8];     // per-wave row-sum partials
  __shared__ float rsum[32];

  const int id = blockIdx.x;
  const int g = id >> 3;
  const int qt = g % 12;
  const int bh = (id & 7) + 8 * (g / 12);
  const int b = bh / H_, h = bh % H_;
  const int i0 = qt * 32;
  const int tid = threadIdx.x, wid = tid >> 6, lane = tid & 63;
  const int lm = lane & 15, quad = lane >> 4;

  const size_t qr0 = ((size_t)(b * S_ + i0 + lm)) * D_ + h * DH_;
  const size_t qr1 = qr0 + (size_t)16 * D_;

  // ---- Q fragments: time-shared registers (qv for loop A, qu for loop B) ----
  short8 q0a = *(const short8*)(qv + qr0 + quad * 8);
  short8 q0b = *(const short8*)(qv + qr0 + 32 + quad * 8);
  short8 q1a = *(const short8*)(qv + qr1 + quad * 8);
  short8 q1b = *(const short8*)(qv + qr1 + 32 + quad * 8);

  // pre-issue first kb unit load (j = wid): in flight during all of loop A
  const u16* kbase = kb + ((size_t)(b * S_ + lm)) * D_ + h * DH_ + quad * 8;
  short8 k0, k1;
  {
    const u16* p = kbase + (size_t)wid * 16 * D_;
    k0 = *(const short8*)p;
    k1 = *(const short8*)(p + 32);
  }

  // ---- loop A: rb units (B_D) -> scatter into scB at reversed positions ----
  short8 b0, b1;
  {
    // first unit m = wid (<8): t <= 479 < 766, no clamp needed
    const int t = i0 + 16 * wid + lm;
    const u16* p = rb + (size_t)t * D_ + h * DH_ + quad * 8;
    b0 = *(const short8*)p;
    b1 = *(const short8*)(p + 32);
  }
  for (int m = wid; m < 26; m += 8) {
    short8 n0 = b0, n1 = b1;
    const int mn = m + 8;
    if (mn < 26) {
      int t = i0 + 16 * mn + lm;
      if (t > 766) t = 766;
      const u16* pn = rb + (size_t)t * D_ + h * DH_ + quad * 8;
      n0 = *(const short8*)pn;
      n1 = *(const short8*)(pn + 32);
    }
    if (m <= 24) {
      floatx4 e = (floatx4){0.f, 0.f, 0.f, 0.f};
      e = __builtin_amdgcn_mfma_f32_16x16x32_bf16(q0a, b0, e, 0, 0, 0);
      e = __builtin_amdgcn_mfma_f32_16x16x32_bf16(q0b, b1, e, 0, 0, 0);
#pragma unroll
      for (int r = 0; r < 4; ++r) {
        const int row = quad * 4 + r;
        const int cp = row + 383 - (16 * m + lm);   // e-idx = 16m+lm
        if (cp >= 0) scB[row * 408 + cp] = f2b(e[r]);
      }
    }
    if (m >= 1) {
      floatx4 e = (floatx4){0.f, 0.f, 0.f, 0.f};
      e = __builtin_amdgcn_mfma_f32_16x16x32_bf16(q1a, b0, e, 0, 0, 0);
      e = __builtin_amdgcn_mfma_f32_16x16x32_bf16(q1b, b1, e, 0, 0, 0);
#pragma unroll
      for (int r = 0; r < 4; ++r) {
        const int row = quad * 4 + r;                // row&15 of (16+row)
        const int cp = row + 399 - 16 * m - lm;      // e-idx = 16(m-1)+lm
        if (cp >= 0) scB[(16 + row) * 408 + cp] = f2b(e[r]);
      }
    }
    b0 = n0;
    b1 = n1;
  }

  // ---- swap Q fragments: qu replaces qv in the same registers ----
  q0a = *(const short8*)(qu + qr0 + quad * 8);
  q0b = *(const short8*)(qu + qr0 + 32 + quad * 8);
  q1a = *(const short8*)(qu + qr1 + quad * 8);
  q1b = *(const short8*)(qu + qr1 + 32 + quad * 8);

  __syncthreads();  // barrier 0: all B_D scatter complete before A_C RMW

  // ---- loop B: kb units (A_C) + fused softmax: P written in place ----
  float psum[8];
#pragma unroll
  for (int r = 0; r < 8; ++r) psum[r] = 0.f;
  b0 = k0;
  b1 = k1;
  for (int j = wid; j < 24; j += 8) {
    short8 n0 = b0, n1 = b1;
    const int jn = j + 8;
    if (jn < 24) {
      const u16* pn = kbase + (size_t)jn * 16 * D_;
      n0 = *(const short8*)pn;
      n1 = *(const short8*)(pn + 32);
    }
    floatx4 e0 = (floatx4){0.f, 0.f, 0.f, 0.f};
    e0 = __builtin_amdgcn_mfma_f32_16x16x32_bf16(q0a, b0, e0, 0, 0, 0);
    e0 = __builtin_amdgcn_mfma_f32_16x16x32_bf16(q0b, b1, e0, 0, 0, 0);
    floatx4 e1 = (floatx4){0.f, 0.f, 0.f, 0.f};
    e1 = __builtin_amdgcn_mfma_f32_16x16x32_bf16(q1a, b0, e1, 0, 0, 0);
    e1 = __builtin_amdgcn_mfma_f32_16x16x32_bf16(q1b, b1, e1, 0, 0, 0);
    const int c = 16 * j + lm;
#pragma unroll
    for (int r = 0; r < 4; ++r) {
      const int o0 = (quad * 4 + r) * 408 + c;
      const int o1 = (16 + quad * 4 + r) * 408 + c;
      const float p0 = __expf((e0[r] + b2f(scB[o0])) * 0.125f);
      scB[o0] = f2b(p0);
      psum[r] += p0;
      const float p1 = __expf((e1[r] + b2f(scB[o1])) * 0.125f);
      scB[o1] = f2b(p1);
      psum[4 + r] += p1;
    }
    b0 = n0;
    b1 = n1;
  }
  // reduce psum over the 16-lane quad group (rows are quad-owned within wave)
#pragma unroll
  for (int m = 1; m < 16; m <<= 1) {
#pragma unroll
    for (int r = 0; r < 8; ++r) psum[r] += __shfl_xor(psum[r], m);
  }
  if (lm == 0) {
#pragma unroll
    for (int r = 0; r < 4; ++r) {
      rp[quad * 4 + r][wid] = psum[r];
      rp[16 + quad * 4 + r][wid] = psum[4 + r];
    }
  }

  __syncthreads();  // barrier 1: P and rp complete

  // ---- mini-pass: finish row sums across the 8 waves ----
  if (tid < 32) {
    float s = 0.f;
#pragma unroll
    for (int w = 0; w < 8; ++w) s += rp[tid][w];
    rsum[tid] = s;
  }
  __syncthreads();  // barrier 2

  // ---- phase 3: PV, vt loaded inline (scheduler hoists within budget) ----
  {
    const int rg = wid & 1, nt = wid >> 1;
    const size_t vbase = ((size_t)(b * D_ + h * DH_ + nt * 16 + lm)) * S_;
    floatx4 oA = (floatx4){0.f, 0.f, 0.f, 0.f};
    floatx4 oB = (floatx4){0.f, 0.f, 0.f, 0.f};
    const int pbase = (rg * 16 + lm) * 408;
#pragma unroll
    for (int kk = 0; kk < 12; kk += 2) {
      const short8 bvA = *(const short8*)(vt + vbase + kk * 32 + quad * 8);
      const short8 afA = *(const short8*)(&scB[pbase + kk * 32 + quad * 8]);
      oA = __builtin_amdgcn_mfma_f32_16x16x32_bf16(afA, bvA, oA, 0, 0, 0);
      const short8 bvB = *(const short8*)(vt + vbase + (kk + 1) * 32 + quad * 8);
      const short8 afB = *(const short8*)(&scB[pbase + (kk + 1) * 32 + quad * 8]);
      oB = __builtin_amdgcn_mfma_f32_16x16x32_bf16(afB, bvB, oB, 0, 0, 0);
    }
#pragma unroll
    for (int r = 0; r < 4; ++r) {
      const int row = rg * 16 + quad * 4 + r;
      attn[((size_t)(b * S_ + i0 + row)) * D_ + h * DH_ + nt * 16 + lm] =
          f2b((oA[r] + oB[r]) / rsum[row]);
    }
  }
}

// ---------------- row layernorm ----------------
__global__ __launch_bounds__(256) void ln_kernel(const u16* __restrict__ y,
                                                 const u16* __restrict__ g,
                                                 const u16* __restrict__ bb,
                                                 void* __restrict__ outv,
                                                 const int* __restrict__ flag, int dual) {
  const int row = blockIdx.x * 4 + (threadIdx.x >> 6);
  const int lane = threadIdx.x & 63;
  const u16* yr = y + (size_t)row * D_;
  float vbuf[12], s = 0.f, s2 = 0.f;
#pragma unroll
  for (int i = 0; i < 12; ++i) {
    const float x = b2f(yr[lane + i * 64]);
    vbuf[i] = x;
    s += x;
    s2 += x * x;
  }
#pragma unroll
  for (int off = 32; off; off >>= 1) {
    s += __shfl_down(s, off);
    s2 += __shfl_down(s2, off);
  }
  s = __shfl(s, 0);
  s2 = __shfl(s2, 0);
  const float mean = s * (1.f / 768.f);
  const float var = s2 * (1.f / 768.f) - mean * mean;
  const float inv = rsqrtf(var + 1e-5f);
  const int f32out = dual && *flag;
#pragma unroll
  for (int i = 0; i < 12; ++i) {
    const int c = lane + i * 64;
    const float val = (vbuf[i] - mean) * inv * b2f(g[c]) + b2f(bb[c]);
    if (f32out) ((float*)outv)[(size_t)row * D_ + c] = val;
    else ((u16*)outv)[(size_t)row * D_ + c] = f2b(val);
  }
}

// ---------------- host ----------------
extern "C" void kernel_launch(void* const* d_in, const int* in_sizes, int n_in,
                              void* d_out, int out_size, void* d_ws, size_t ws_size,
                              hipStream_t stream) {
  const void* x    = d_in[0];
  const void* pe   = d_in[1];
  const void* Wq   = d_in[2];
  const void* Wk   = d_in[3];
  const void* Wv   = d_in[4];
  const void* Wr   = d_in[5];
  const void* ub   = d_in[6];
  const void* vb   = d_in[7];
  const void* Wo   = d_in[8];
  const void* ln1g = d_in[9];
  const void* ln1b = d_in[10];
  const void* ln2g = d_in[11];
  const void* ln2b = d_in[12];
  const void* W1   = d_in[13];
  const void* b1   = d_in[14];
  const void* W2   = d_in[15];
  const void* b2   = d_in[16];
  char* ws = (char*)d_ws;

  constexpr size_t O_W   = 0;
  constexpr size_t O_SM  = 15335424;
  constexpr size_t O_XB  = 15368192;
  constexpr size_t O_QU  = 24805376;
  constexpr size_t O_QV  = 34242560;
  constexpr size_t O_KB  = 43679744;
  constexpr size_t O_VT  = 53116928;
  constexpr size_t O_RB  = 62554112;
  constexpr size_t NEEDED = 63733760;

  if (ws_size < NEEDED) {
    fill_sentinel<<<(out_size + 255) / 256, 256, 0, stream>>>((u16*)d_out, out_size);
    return;
  }

  int* flag = (int*)(ws + O_SM);
  u16* ubc  = (u16*)(ws + O_SM + 128);
  u16* vbc  = (u16*)(ws + O_SM + 1664);
  u16* b1c  = (u16*)(ws + O_SM + 3200);
  u16* b2c  = (u16*)(ws + O_SM + 9344);
  u16* g1c  = (u16*)(ws + O_SM + 10880);
  u16* be1c = (u16*)(ws + O_SM + 12416);
  u16* g2c  = (u16*)(ws + O_SM + 13952);
  u16* be2c = (u16*)(ws + O_SM + 15488);

  u16* wtq = (u16*)(ws + O_W);   // wtq|wtk|wtv contiguous = fused QKV B
  u16* wtk = wtq + (size_t)D_ * D_;
  u16* wtv = wtk + (size_t)D_ * D_;
  u16* wtr = wtv + (size_t)D_ * D_;
  u16* wto = wtr + (size_t)D_ * D_;
  u16* wt1 = wto + (size_t)D_ * D_;
  u16* wt2 = wt1 + (size_t)D_ * FF_;

  u16* xb  = (u16*)(ws + O_XB);
  u16* quB = (u16*)(ws + O_QU);
  u16* qvB = (u16*)(ws + O_QV);
  u16* kbB = (u16*)(ws + O_KB);
  u16* vtB = (u16*)(ws + O_VT);
  u16* rbB = (u16*)(ws + O_RB);
  u16* peb = (u16*)d_out;          // pe lives in d_out until QKV+rproj completes
  u16* atB = (u16*)d_out;          // attn out overwrites peb afterwards (serial)
  u16* y1B = xb;
  u16* x1B = (u16*)(ws + O_VT);
  u16* ffB = xb;
  u16* y2B = x1B;

  TP tp;
  tp.src[0] = Wq; tp.src[1] = Wk; tp.src[2] = Wv; tp.src[3] = Wr; tp.src[4] = Wo;
  tp.src[5] = W1; tp.src[6] = W2;
  tp.dst[0] = wtq; tp.dst[1] = wtk; tp.dst[2] = wtv; tp.dst[3] = wtr; tp.dst[4] = wto;
  tp.dst[5] = wt1; tp.dst[6] = wt2;

  // 1) all conversions + transposes + dtype flag in one dispatch
  preamble_all<<<12705, 256, 0, stream>>>(tp, x, pe, b1, ub, vb, b2, ln1g, ln1b,
                                          ln2g, ln2b, xb, peb, b1c, ubc, vbc, b2c,
                                          g1c, be1c, g2c, be2c, flag);
  // 2) fused QKV (TN=64, supertile-swizzled: 1728 blocks) + r-proj (72)
  gemm_qkv_rp<<<1800, 256, 0, stream>>>(xb, wtq, peb, wtr, quB, qvB, kbB, vtB, rbB,
                                        ubc, vbc);
  // 3) attention -> d_out scratch
  attn_kernel<<<2304, 512, 0, stream>>>(quB, qvB, kbB, vtB, rbB, atB);
  // 4) Wo + residual — 64x64 tiles: grid (12,96)=1152 blocks
  gemm3<64, 64, 32, 32, F_RES, 1><<<dim3(12, 96), 256, 0, stream>>>(
      atB, wto, y1B, nullptr, xb, B_ * S_, D_, D_);
  ln_kernel<<<B_ * S_ / 4, 256, 0, stream>>>(y1B, g1c, be1c, x1B, flag, 0);
  // 5) FFN1 — 128x64 tiles + supertile swizzle: grid (48,48)=2304 blocks
  gemm3<128, 64, 64, 32, F_BIAS | F_RELU, 2><<<dim3(48, 48), 256, 0, stream>>>(
      x1B, wt1, ffB, b1c, nullptr, B_ * S_, FF_, D_);
  // 6) FFN2 — 64x64 tiles: grid (12,96)=1152 blocks
  gemm3<64, 64, 32, 32, F_BIAS | F_RES, 1><<<dim3(12, 96), 256, 0, stream>>>(
      ffB, wt2, y2B, b2c, x1B, B_ * S_, D_, FF_);
  ln_kernel<<<B_ * S_ / 4, 256, 0, stream>>>(y2B, g2c, be2c, d_out, flag, 1);
}

// Round 12
// 399.116 us; speedup vs baseline: 1.0923x; 1.0118x over previous
//
#include <hip/hip_runtime.h>

typedef unsigned short u16;
typedef __attribute__((ext_vector_type(8))) short short8;
typedef __attribute__((ext_vector_type(4))) float floatx4;

#define B_  16
#define S_  384
#define D_  768
#define H_  12
#define DH_ 64
#define FF_ 3072

__device__ __forceinline__ float b2f(u16 h) { return __uint_as_float(((unsigned)h) << 16); }
__device__ __forceinline__ u16 f2b(float f) {
  unsigned u = __float_as_uint(f);
  u += 0x7fffu + ((u >> 16) & 1u);
  return (u16)(u >> 16);
}

__device__ __forceinline__ void gload16(const u16* g, u16* l) {
  __builtin_amdgcn_global_load_lds(
      (const __attribute__((address_space(1))) unsigned int*)g,
      (__attribute__((address_space(3))) unsigned int*)l, 16, 0, 0);
}

__global__ __launch_bounds__(256) void fill_sentinel(u16* out, int n) {
  int i = blockIdx.x * 256 + threadIdx.x;
  if (i < n) out[i] = 0x42DE;  // bf16 111.0
}

// inline dtype detect: 256 u16 of x; fp32 low-halves hit exp>=0xC0 w.p. 0.25
__device__ __forceinline__ int detect_flag(const u16* x, int tid, int* sh) {
  const unsigned e = (x[tid] >> 7) & 0xFFu;
  const unsigned long long m = __ballot(e >= 0xC0u);
  if ((tid & 63) == 0) sh[tid >> 6] = (m != 0ull) ? 1 : 0;
  __syncthreads();
  return sh[0] | sh[1] | sh[2] | sh[3];
}

// ---------------- mega-preamble v2: VECTORIZED transposes + converts + flag ----------------
// Transposes were 32x32 tiles with 4 scalar u16 global stores/thread (64 B/wave-inst,
// ~16x under-vectorized). v2: 64x64 tiles, float4/ushort4 loads, ushort4 stores.
// Blocks for transposes: 7488 -> 1872. Grid: 12705 -> 7089.
struct TP { const void* src[7]; u16* dst[7]; };
__global__ __launch_bounds__(256) void preamble_all(
    TP tp, const void* x, const void* pe,
    const void* b1, const void* ub, const void* vb, const void* b2,
    const void* g1, const void* be1, const void* g2, const void* be2,
    u16* xb, u16* peb,
    u16* b1c, u16* ubc, u16* vbc, u16* b2c,
    u16* g1c, u16* be1c, u16* g2c, u16* be2c, int* flag_ws) {
  __shared__ u16 T[64][68];
  __shared__ int fl[4];
  const int tid = threadIdx.x;
  const int f32 = detect_flag((const u16*)x, tid, fl);
  const int id = blockIdx.x;
  if (id == 0 && tid == 0) *flag_ws = f32;  // for ln_kernel's output dtype

  if (id < 1872) {  // weight transposes, 64x64 vectorized
    int w, tt, R, C, bc, br;
    if (id < 720)       { w = id / 144; tt = id % 144;  R = 768;  C = 768;  bc = (tt % 12) * 64; br = (tt / 12) * 64; }
    else if (id < 1296) { w = 5;        tt = id - 720;  R = 768;  C = 3072; bc = (tt % 48) * 64; br = (tt / 48) * 64; }
    else                { w = 6;        tt = id - 1296; R = 3072; C = 768;  bc = (tt % 12) * 64; br = (tt / 12) * 64; }
    const void* in = tp.src[w];
    u16* out = tp.dst[w];
    const int tx4 = (tid & 15) * 4, ty = tid >> 4;  // ty in [0,16)
#pragma unroll
    for (int p = 0; p < 4; ++p) {
      const int row = ty + p * 16;
      const size_t base = (size_t)(br + row) * C + bc + tx4;
      ushort4 o;
      if (f32) {
        const float4 f = *(const float4*)((const float*)in + base);
        o.x = f2b(f.x); o.y = f2b(f.y); o.z = f2b(f.z); o.w = f2b(f.w);
      } else {
        o = *(const ushort4*)((const u16*)in + base);
      }
      *(ushort4*)&T[row][tx4] = o;
    }
    __syncthreads();
#pragma unroll
    for (int p = 0; p < 4; ++p) {
      const int oc = ty + p * 16;
      ushort4 o;
      o.x = T[tx4 + 0][oc];
      o.y = T[tx4 + 1][oc];
      o.z = T[tx4 + 2][oc];
      o.w = T[tx4 + 3][oc];
      *(ushort4*)(out + (size_t)(bc + oc) * R + br + tx4) = o;
    }
  } else if (id < 6480) {  // x convert (4-wide)
    const int i = (id - 1872) * 256 + tid;
    if (i < B_ * S_ * D_ / 4) {
      if (f32) {
        const float4 f = ((const float4*)x)[i];
        ushort4 o;
        o.x = f2b(f.x); o.y = f2b(f.y); o.z = f2b(f.z); o.w = f2b(f.w);
        ((ushort4*)xb)[i] = o;
      } else {
        ((ushort4*)xb)[i] = ((const ushort4*)x)[i];
      }
    }
  } else if (id < 7056) {  // pe convert
    const int i = (id - 6480) * 256 + tid;
    if (i < (2 * S_ - 1) * D_ / 4) {
      if (f32) {
        const float4 f = ((const float4*)pe)[i];
        ushort4 o;
        o.x = f2b(f.x); o.y = f2b(f.y); o.z = f2b(f.z); o.w = f2b(f.w);
        ((ushort4*)peb)[i] = o;
      } else {
        ((ushort4*)peb)[i] = ((const ushort4*)pe)[i];
      }
    }
  } else {  // small tensors
    const int i = (id - 7056) * 256 + tid;
    if (i < 8448) {
      const void* s; u16* d; int off;
      if (i < 3072) { s = b1; d = b1c; off = i; }
      else {
        const int r = i - 3072, sg = r / 768; off = r - sg * 768;
        switch (sg) {
          case 0: s = ub;  d = ubc;  break;
          case 1: s = vb;  d = vbc;  break;
          case 2: s = b2;  d = b2c;  break;
          case 3: s = g1;  d = g1c;  break;
          case 4: s = be1; d = be1c; break;
          case 5: s = g2;  d = g2c;  break;
          default: s = be2; d = be2c; break;
        }
      }
      d[off] = f32 ? f2b(((const float*)s)[off]) : ((const u16*)s)[off];
    }
  }
}

// ---------------- GEMM v3: XOR-swizzled LDS + prefetch ----------------
// SWZ=1: XCD-chunked 1D swizzle (consecutive ids share an XCD chunk).
// SWZ=2: 2D supertile XCD swizzle — XCD c = d%8 owns a contiguous SX x SY
//   block subtile (SX=gx/2, SY=gy/4), so per-XCD L2 working set = A-sub +
//   B-sub (both ~2.25 MB at 128x64/K=768) < 4 MB L2. Requires gx%2==0, gy%4==0.
enum { F_BIAS = 1, F_RELU = 2, F_RES = 4 };

template <int TM, int TN, int WM, int WN, int FLAGS, int SWZ>
__global__ __launch_bounds__(256) void gemm3(
    const u16* __restrict__ A, const u16* __restrict__ Bt,
    u16* __restrict__ out0, const u16* __restrict__ bias0,
    const u16* __restrict__ res, int M, int N, int K) {
  constexpr int WAVES_M = TM / WM;
  constexpr int MT = WM / 16, NT = WN / 16;
  constexpr int NI = (TM + TN) / 64;
  static_assert((TM / WM) * (TN / WN) == 4, "4 waves");
  __shared__ u16 SM[2][(TM + TN) * 32];

  int bxx = blockIdx.x, byy = blockIdx.y;
  if (SWZ == 1) {
    const int gx = gridDim.x;
    const int nwg = gx * gridDim.y;
    if (!(nwg & 7)) {
      const int q = nwg >> 3;
      const int d = byy * gx + bxx;
      const int id = (d & 7) * q + (d >> 3);
      bxx = id % gx;
      byy = id / gx;
    }
  } else if (SWZ == 2) {
    const int gx = gridDim.x;
    const int SX = gx >> 1, SY = gridDim.y >> 2;
    const int d = byy * gx + bxx;
    const int c = d & 7, r = d >> 3;
    bxx = (c & 1) * SX + r % SX;
    byy = (c >> 1) * SY + r / SX;
  }
  const int m0 = byy * TM;
  const int n0 = bxx * TN;
  const int tid = threadIdx.x;
  const int wid = tid >> 6, lane = tid & 63;
  const int wm = (wid % WAVES_M) * WM, wn = (wid / WAVES_M) * WN;
  const int lm = lane & 15, quad = lane >> 4;

  floatx4 acc[MT][NT];
#pragma unroll
  for (int i = 0; i < MT; ++i)
#pragma unroll
    for (int j = 0; j < NT; ++j) acc[i][j] = (floatx4){0.f, 0.f, 0.f, 0.f};

  const u16* srcs[NI];
  int ldso[NI];
#pragma unroll
  for (int i = 0; i < NI; ++i) {
    const int j = wid + 4 * i;
    const int r = j * 16 + (lane >> 2);
    const int q = (lane & 3) ^ ((r >> 1) & 3);
    const u16* p;
    if (r < TM) {
      int ga = m0 + r;
      if (ga > M - 1) ga = M - 1;
      p = A + (size_t)ga * K + q * 8;
    } else {
      p = Bt + (size_t)(n0 + r - TM) * K + q * 8;
    }
    srcs[i] = p;
    ldso[i] = j * 512;
  }
  const int slot = (quad ^ ((lm >> 1) & 3)) * 8;
  int aoff[MT], boff[NT];
#pragma unroll
  for (int t = 0; t < MT; ++t) aoff[t] = (wm + t * 16 + lm) * 32 + slot;
#pragma unroll
  for (int t = 0; t < NT; ++t) boff[t] = (TM + wn + t * 16 + lm) * 32 + slot;

#pragma unroll
  for (int i = 0; i < NI; ++i) gload16(srcs[i], &SM[0][ldso[i]]);
  __syncthreads();

  int buf = 0;
  for (int k0 = 0; k0 < K; k0 += 32, buf ^= 1) {
    if (k0 + 32 < K) {
      const int koff = (k0 + 32);
#pragma unroll
      for (int i = 0; i < NI; ++i) gload16(srcs[i] + koff, &SM[buf ^ 1][ldso[i]]);
    }
    short8 af[MT], bf[NT];
#pragma unroll
    for (int t = 0; t < MT; ++t) af[t] = *(const short8*)(&SM[buf][aoff[t]]);
#pragma unroll
    for (int t = 0; t < NT; ++t) bf[t] = *(const short8*)(&SM[buf][boff[t]]);
#pragma unroll
    for (int tm = 0; tm < MT; ++tm)
#pragma unroll
      for (int tn = 0; tn < NT; ++tn)
        acc[tm][tn] = __builtin_amdgcn_mfma_f32_16x16x32_bf16(af[tm], bf[tn], acc[tm][tn], 0, 0, 0);
    __syncthreads();
  }

#pragma unroll
  for (int tm = 0; tm < MT; ++tm) {
#pragma unroll
    for (int tn = 0; tn < NT; ++tn) {
      const int gcol = n0 + wn + tn * 16 + lm;
#pragma unroll
      for (int r = 0; r < 4; ++r) {
        const int grow = m0 + wm + tm * 16 + quad * 4 + r;
        if (grow >= M) continue;
        float val = acc[tm][tn][r];
        if (FLAGS & F_BIAS) val += b2f(bias0[gcol]);
        if (FLAGS & F_RES) val += b2f(res[(size_t)grow * N + gcol]);
        if (FLAGS & F_RELU) val = fmaxf(val, 0.f);
        out0[(size_t)grow * N + gcol] = f2b(val);
      }
    }
  }
}

// ---------------- fused QKV (region epilogue + vt LDS-bounce) + r-proj ----------------
// v3: TN=64 (TM=128, WM=64, WN=32) + 2D supertile XCD swizzle for the QKV part:
// c = id%8 owns an 18x12 block subtile (A-sub 2.25 MB + B-sub 1.7 MB < 4 MB L2).
// Grid 1800: id<1728 -> QKV (36x48, N=2304); else -> r-proj (12x6, M=767).
__global__ __launch_bounds__(256) void gemm_qkv_rp(
    const u16* __restrict__ xb, const u16* __restrict__ wqkv,
    const u16* __restrict__ peb, const u16* __restrict__ wtr,
    u16* __restrict__ qu, u16* __restrict__ qv,
    u16* __restrict__ kbo, u16* __restrict__ vto, u16* __restrict__ rbo,
    const u16* __restrict__ ubias, const u16* __restrict__ vbias) {
  constexpr int TM = 128, TN = 64, WM = 64, WN = 32;
  constexpr int MT = 4, NT = 2, NI = 3;
  __shared__ u16 SM[2][(TM + TN) * 32];

  const int id = blockIdx.x;
  const int qkv = (id < 1728) ? 1 : 0;
  int bx, by, M;
  const u16 *A, *Bt;
  if (qkv) {
    // supertile: XCD c = id%8 gets subtile (c&1, c>>1) of 18x12 blocks
    const int c = id & 7, r = id >> 3;  // r in [0,216)
    bx = (c & 1) * 18 + r % 18;
    by = (c >> 1) * 12 + r / 18;
    M = B_ * S_; A = xb; Bt = wqkv;
  } else {
    const int t2 = id - 1728; bx = t2 % 12; by = t2 / 12; M = 767; A = peb; Bt = wtr;
  }
  const int K = 768;
  const int m0 = by * TM, n0 = bx * TN;
  const int tid = threadIdx.x;
  const int wid = tid >> 6, lane = tid & 63;
  const int wm = (wid & 1) * WM, wn = (wid >> 1) * WN;
  const int lm = lane & 15, quad = lane >> 4;

  floatx4 acc[MT][NT];
#pragma unroll
  for (int i = 0; i < MT; ++i)
#pragma unroll
    for (int j = 0; j < NT; ++j) acc[i][j] = (floatx4){0.f, 0.f, 0.f, 0.f};

  const u16* srcs[NI];
  int ldso[NI];
#pragma unroll
  for (int i = 0; i < NI; ++i) {
    const int j = wid + 4 * i;
    const int r = j * 16 + (lane >> 2);
    const int q = (lane & 3) ^ ((r >> 1) & 3);
    const u16* p;
    if (r < TM) {
      int ga = m0 + r;
      if (ga > M - 1) ga = M - 1;
      p = A + (size_t)ga * K + q * 8;
    } else {
      p = Bt + (size_t)(n0 + r - TM) * K + q * 8;
    }
    srcs[i] = p;
    ldso[i] = j * 512;
  }
  const int slot = (quad ^ ((lm >> 1) & 3)) * 8;
  int aoff[MT], boff[NT];
#pragma unroll
  for (int t = 0; t < MT; ++t) aoff[t] = (wm + t * 16 + lm) * 32 + slot;
#pragma unroll
  for (int t = 0; t < NT; ++t) boff[t] = (TM + wn + t * 16 + lm) * 32 + slot;

#pragma unroll
  for (int i = 0; i < NI; ++i) gload16(srcs[i], &SM[0][ldso[i]]);
  __syncthreads();

  int buf = 0;
  for (int k0 = 0; k0 < K; k0 += 32, buf ^= 1) {
    if (k0 + 32 < K) {
      const int koff = (k0 + 32);
#pragma unroll
      for (int i = 0; i < NI; ++i) gload16(srcs[i] + koff, &SM[buf ^ 1][ldso[i]]);
    }
    short8 af[MT], bf[NT];
#pragma unroll
    for (int t = 0; t < MT; ++t) af[t] = *(const short8*)(&SM[buf][aoff[t]]);
#pragma unroll
    for (int t = 0; t < NT; ++t) bf[t] = *(const short8*)(&SM[buf][boff[t]]);
#pragma unroll
    for (int tm = 0; tm < MT; ++tm)
#pragma unroll
      for (int tn = 0; tn < NT; ++tn)
        acc[tm][tn] = __builtin_amdgcn_mfma_f32_16x16x32_bf16(af[tm], bf[tn], acc[tm][tn], 0, 0, 0);
    __syncthreads();
  }

  if (!qkv) {  // r-proj plain store
#pragma unroll
    for (int tm = 0; tm < MT; ++tm)
#pragma unroll
      for (int tn = 0; tn < NT; ++tn) {
        const int gcol = n0 + wn + tn * 16 + lm;
#pragma unroll
        for (int r = 0; r < 4; ++r) {
          const int grow = m0 + wm + tm * 16 + quad * 4 + r;
          if (grow < M) rbo[(size_t)grow * 768 + gcol] = f2b(acc[tm][tn][r]);
        }
      }
    return;
  }
  // QKV epilogue; region is block-uniform (768 % 64 == 0)
  const int region = n0 / 768;
  if (region == 2) {
    // vt: coalesced store via per-wave LDS bounce (SM dead after last barrier)
    u16* wbuf = &SM[0][0] + wid * 1088;  // [64][17]
    const int bb = (m0 + wm) / S_;
    const int sbase = (m0 + wm) % S_;
    const int cl = lane >> 2, sc = (lane & 3) * 16;
#pragma unroll
    for (int tn = 0; tn < NT; ++tn) {
#pragma unroll
      for (int tm = 0; tm < MT; ++tm)
#pragma unroll
        for (int r = 0; r < 4; ++r)
          wbuf[(tm * 16 + quad * 4 + r) * 17 + lm] = f2b(acc[tm][tn][r]);
      short8 s0, s1;
#pragma unroll
      for (int j = 0; j < 8; ++j) s0[j] = (short)wbuf[(sc + j) * 17 + cl];
#pragma unroll
      for (int j = 0; j < 8; ++j) s1[j] = (short)wbuf[(sc + 8 + j) * 17 + cl];
      const int cglob = n0 - 1536 + wn + tn * 16 + cl;
      u16* dst = vto + ((size_t)(bb * D_ + cglob)) * S_ + sbase + sc;
      *(short8*)dst = s0;
      *(short8*)(dst + 8) = s1;
    }
    return;
  }
#pragma unroll
  for (int tm = 0; tm < MT; ++tm) {
#pragma unroll
    for (int tn = 0; tn < NT; ++tn) {
      const int gcol = n0 + wn + tn * 16 + lm;
      const int c = gcol - region * 768;
#pragma unroll
      for (int r = 0; r < 4; ++r) {
        const int grow = m0 + wm + tm * 16 + quad * 4 + r;
        const float val = acc[tm][tn][r];
        if (region == 0) {
          qu[(size_t)grow * 768 + c] = f2b(val + b2f(ubias[c]));
          qv[(size_t)grow * 768 + c] = f2b(val + b2f(vbias[c]));
        } else {
          kbo[(size_t)grow * 768 + c] = f2b(val);
        }
      }
    }
  }
}

// ---------------- attention v14 (verified r11): Eb-elim + softmax fused into loop B ----------------
// LDS: scB 26112 + rp 1024 + rsum 128 = 27264 B. Pinned at ~75 us across v10/v12/v14
// (occupancy-, VALU-, and LDS-insensitive) — left untouched.
__global__ __launch_bounds__(512, 6) void attn_kernel(
    const u16* __restrict__ qu, const u16* __restrict__ qv,
    const u16* __restrict__ kb, const u16* __restrict__ vt,
    const u16* __restrict__ rb, u16* __restrict__ attn) {
  __shared__ u16 scB[32 * 408];   // B_D scatter, then P (bf16) in place
  __shared__ float rp[32][8];     // per-wave row-sum partials
  __shared__ float rsum[32];

  const int id = blockIdx.x;
  const int g = id >> 3;
  const int qt = g % 12;
  const int bh = (id & 7) + 8 * (g / 12);
  const int b = bh / H_, h = bh % H_;
  const int i0 = qt * 32;
  const int tid = threadIdx.x, wid = tid >> 6, lane = tid & 63;
  const int lm = lane & 15, quad = lane >> 4;

  const size_t qr0 = ((size_t)(b * S_ + i0 + lm)) * D_ + h * DH_;
  const size_t qr1 = qr0 + (size_t)16 * D_;

  // ---- Q fragments: time-shared registers (qv for loop A, qu for loop B) ----
  short8 q0a = *(const short8*)(qv + qr0 + quad * 8);
  short8 q0b = *(const short8*)(qv + qr0 + 32 + quad * 8);
  short8 q1a = *(const short8*)(qv + qr1 + quad * 8);
  short8 q1b = *(const short8*)(qv + qr1 + 32 + quad * 8);

  // pre-issue first kb unit load (j = wid): in flight during all of loop A
  const u16* kbase = kb + ((size_t)(b * S_ + lm)) * D_ + h * DH_ + quad * 8;
  short8 k0, k1;
  {
    const u16* p = kbase + (size_t)wid * 16 * D_;
    k0 = *(const short8*)p;
    k1 = *(const short8*)(p + 32);
  }

  // ---- loop A: rb units (B_D) -> scatter into scB at reversed positions ----
  short8 b0, b1;
  {
    // first unit m = wid (<8): t <= 479 < 766, no clamp needed
    const int t = i0 + 16 * wid + lm;
    const u16* p = rb + (size_t)t * D_ + h * DH_ + quad * 8;
    b0 = *(const short8*)p;
    b1 = *(const short8*)(p + 32);
  }
  for (int m = wid; m < 26; m += 8) {
    short8 n0 = b0, n1 = b1;
    const int mn = m + 8;
    if (mn < 26) {
      int t = i0 + 16 * mn + lm;
      if (t > 766) t = 766;
      const u16* pn = rb + (size_t)t * D_ + h * DH_ + quad * 8;
      n0 = *(const short8*)pn;
      n1 = *(const short8*)(pn + 32);
    }
    if (m <= 24) {
      floatx4 e = (floatx4){0.f, 0.f, 0.f, 0.f};
      e = __builtin_amdgcn_mfma_f32_16x16x32_bf16(q0a, b0, e, 0, 0, 0);
      e = __builtin_amdgcn_mfma_f32_16x16x32_bf16(q0b, b1, e, 0, 0, 0);
#pragma unroll
      for (int r = 0; r < 4; ++r) {
        const int row = quad * 4 + r;
        const int cp = row + 383 - (16 * m + lm);   // e-idx = 16m+lm
        if (cp >= 0) scB[row * 408 + cp] = f2b(e[r]);
      }
    }
    if (m >= 1) {
      floatx4 e = (floatx4){0.f, 0.f, 0.f, 0.f};
      e = __builtin_amdgcn_mfma_f32_16x16x32_bf16(q1a, b0, e, 0, 0, 0);
      e = __builtin_amdgcn_mfma_f32_16x16x32_bf16(q1b, b1, e, 0, 0, 0);
#pragma unroll
      for (int r = 0; r < 4; ++r) {
        const int row = quad * 4 + r;                // row&15 of (16+row)
        const int cp = row + 399 - 16 * m - lm;      // e-idx = 16(m-1)+lm
        if (cp >= 0) scB[(16 + row) * 408 + cp] = f2b(e[r]);
      }
    }
    b0 = n0;
    b1 = n1;
  }

  // ---- swap Q fragments: qu replaces qv in the same registers ----
  q0a = *(const short8*)(qu + qr0 + quad * 8);
  q0b = *(const short8*)(qu + qr0 + 32 + quad * 8);
  q1a = *(const short8*)(qu + qr1 + quad * 8);
  q1b = *(const short8*)(qu + qr1 + 32 + quad * 8);

  __syncthreads();  // barrier 0: all B_D scatter complete before A_C RMW

  // ---- loop B: kb units (A_C) + fused softmax: P written in place ----
  float psum[8];
#pragma unroll
  for (int r = 0; r < 8; ++r) psum[r] = 0.f;
  b0 = k0;
  b1 = k1;
  for (int j = wid; j < 24; j += 8) {
    short8 n0 = b0, n1 = b1;
    const int jn = j + 8;
    if (jn < 24) {
      const u16* pn = kbase + (size_t)jn * 16 * D_;
      n0 = *(const short8*)pn;
      n1 = *(const short8*)(pn + 32);
    }
    floatx4 e0 = (floatx4){0.f, 0.f, 0.f, 0.f};
    e0 = __builtin_amdgcn_mfma_f32_16x16x32_bf16(q0a, b0, e0, 0, 0, 0);
    e0 = __builtin_amdgcn_mfma_f32_16x16x32_bf16(q0b, b1, e0, 0, 0, 0);
    floatx4 e1 = (floatx4){0.f, 0.f, 0.f, 0.f};
    e1 = __builtin_amdgcn_mfma_f32_16x16x32_bf16(q1a, b0, e1, 0, 0, 0);
    e1 = __builtin_amdgcn_mfma_f32_16x16x32_bf16(q1b, b1, e1, 0, 0, 0);
    const int c = 16 * j + lm;
#pragma unroll
    for (int r = 0; r < 4; ++r) {
      const int o0 = (quad * 4 + r) * 408 + c;
      const int o1 = (16 + quad * 4 + r) * 408 + c;
      const float p0 = __expf((e0[r] + b2f(scB[o0])) * 0.125f);
      scB[o0] = f2b(p0);
      psum[r] += p0;
      const float p1 = __expf((e1[r] + b2f(scB[o1])) * 0.125f);
      scB[o1] = f2b(p1);
      psum[4 + r] += p1;
    }
    b0 = n0;
    b1 = n1;
  }
  // reduce psum over the 16-lane quad group (rows are quad-owned within wave)
#pragma unroll
  for (int m = 1; m < 16; m <<= 1) {
#pragma unroll
    for (int r = 0; r < 8; ++r) psum[r] += __shfl_xor(psum[r], m);
  }
  if (lm == 0) {
#pragma unroll
    for (int r = 0; r < 4; ++r) {
      rp[quad * 4 + r][wid] = psum[r];
      rp[16 + quad * 4 + r][wid] = psum[4 + r];
    }
  }

  __syncthreads();  // barrier 1: P and rp complete

  // ---- mini-pass: finish row sums across the 8 waves ----
  if (tid < 32) {
    float s = 0.f;
#pragma unroll
    for (int w = 0; w < 8; ++w) s += rp[tid][w];
    rsum[tid] = s;
  }
  __syncthreads();  // barrier 2

  // ---- phase 3: PV, vt loaded inline (scheduler hoists within budget) ----
  {
    const int rg = wid & 1, nt = wid >> 1;
    const size_t vbase = ((size_t)(b * D_ + h * DH_ + nt * 16 + lm)) * S_;
    floatx4 oA = (floatx4){0.f, 0.f, 0.f, 0.f};
    floatx4 oB = (floatx4){0.f, 0.f, 0.f, 0.f};
    const int pbase = (rg * 16 + lm) * 408;
#pragma unroll
    for (int kk = 0; kk < 12; kk += 2) {
      const short8 bvA = *(const short8*)(vt + vbase + kk * 32 + quad * 8);
      const short8 afA = *(const short8*)(&scB[pbase + kk * 32 + quad * 8]);
      oA = __builtin_amdgcn_mfma_f32_16x16x32_bf16(afA, bvA, oA, 0, 0, 0);
      const short8 bvB = *(const short8*)(vt + vbase + (kk + 1) * 32 + quad * 8);
      const short8 afB = *(const short8*)(&scB[pbase + (kk + 1) * 32 + quad * 8]);
      oB = __builtin_amdgcn_mfma_f32_16x16x32_bf16(afB, bvB, oB, 0, 0, 0);
    }
#pragma unroll
    for (int r = 0; r < 4; ++r) {
      const int row = rg * 16 + quad * 4 + r;
      attn[((size_t)(b * S_ + i0 + row)) * D_ + h * DH_ + nt * 16 + lm] =
          f2b((oA[r] + oB[r]) / rsum[row]);
    }
  }
}

// ---------------- row layernorm ----------------
__global__ __launch_bounds__(256) void ln_kernel(const u16* __restrict__ y,
                                                 const u16* __restrict__ g,
                                                 const u16* __restrict__ bb,
                                                 void* __restrict__ outv,
                                                 const int* __restrict__ flag, int dual) {
  const int row = blockIdx.x * 4 + (threadIdx.x >> 6);
  const int lane = threadIdx.x & 63;
  const u16* yr = y + (size_t)row * D_;
  float vbuf[12], s = 0.f, s2 = 0.f;
#pragma unroll
  for (int i = 0; i < 12; ++i) {
    const float x = b2f(yr[lane + i * 64]);
    vbuf[i] = x;
    s += x;
    s2 += x * x;
  }
#pragma unroll
  for (int off = 32; off; off >>= 1) {
    s += __shfl_down(s, off);
    s2 += __shfl_down(s2, off);
  }
  s = __shfl(s, 0);
  s2 = __shfl(s2, 0);
  const float mean = s * (1.f / 768.f);
  const float var = s2 * (1.f / 768.f) - mean * mean;
  const float inv = rsqrtf(var + 1e-5f);
  const int f32out = dual && *flag;
#pragma unroll
  for (int i = 0; i < 12; ++i) {
    const int c = lane + i * 64;
    const float val = (vbuf[i] - mean) * inv * b2f(g[c]) + b2f(bb[c]);
    if (f32out) ((float*)outv)[(size_t)row * D_ + c] = val;
    else ((u16*)outv)[(size_t)row * D_ + c] = f2b(val);
  }
}

// ---------------- host ----------------
extern "C" void kernel_launch(void* const* d_in, const int* in_sizes, int n_in,
                              void* d_out, int out_size, void* d_ws, size_t ws_size,
                              hipStream_t stream) {
  const void* x    = d_in[0];
  const void* pe   = d_in[1];
  const void* Wq   = d_in[2];
  const void* Wk   = d_in[3];
  const void* Wv   = d_in[4];
  const void* Wr   = d_in[5];
  const void* ub   = d_in[6];
  const void* vb   = d_in[7];
  const void* Wo   = d_in[8];
  const void* ln1g = d_in[9];
  const void* ln1b = d_in[10];
  const void* ln2g = d_in[11];
  const void* ln2b = d_in[12];
  const void* W1   = d_in[13];
  const void* b1   = d_in[14];
  const void* W2   = d_in[15];
  const void* b2   = d_in[16];
  char* ws = (char*)d_ws;

  constexpr size_t O_W   = 0;
  constexpr size_t O_SM  = 15335424;
  constexpr size_t O_XB  = 15368192;
  constexpr size_t O_QU  = 24805376;
  constexpr size_t O_QV  = 34242560;
  constexpr size_t O_KB  = 43679744;
  constexpr size_t O_VT  = 53116928;
  constexpr size_t O_RB  = 62554112;
  constexpr size_t NEEDED = 63733760;

  if (ws_size < NEEDED) {
    fill_sentinel<<<(out_size + 255) / 256, 256, 0, stream>>>((u16*)d_out, out_size);
    return;
  }

  int* flag = (int*)(ws + O_SM);
  u16* ubc  = (u16*)(ws + O_SM + 128);
  u16* vbc  = (u16*)(ws + O_SM + 1664);
  u16* b1c  = (u16*)(ws + O_SM + 3200);
  u16* b2c  = (u16*)(ws + O_SM + 9344);
  u16* g1c  = (u16*)(ws + O_SM + 10880);
  u16* be1c = (u16*)(ws + O_SM + 12416);
  u16* g2c  = (u16*)(ws + O_SM + 13952);
  u16* be2c = (u16*)(ws + O_SM + 15488);

  u16* wtq = (u16*)(ws + O_W);   // wtq|wtk|wtv contiguous = fused QKV B
  u16* wtk = wtq + (size_t)D_ * D_;
  u16* wtv = wtk + (size_t)D_ * D_;
  u16* wtr = wtv + (size_t)D_ * D_;
  u16* wto = wtr + (size_t)D_ * D_;
  u16* wt1 = wto + (size_t)D_ * D_;
  u16* wt2 = wt1 + (size_t)D_ * FF_;

  u16* xb  = (u16*)(ws + O_XB);
  u16* quB = (u16*)(ws + O_QU);
  u16* qvB = (u16*)(ws + O_QV);
  u16* kbB = (u16*)(ws + O_KB);
  u16* vtB = (u16*)(ws + O_VT);
  u16* rbB = (u16*)(ws + O_RB);
  u16* peb = (u16*)d_out;          // pe lives in d_out until QKV+rproj completes
  u16* atB = (u16*)d_out;          // attn out overwrites peb afterwards (serial)
  u16* y1B = xb;
  u16* x1B = (u16*)(ws + O_VT);
  u16* ffB = xb;
  u16* y2B = x1B;

  TP tp;
  tp.src[0] = Wq; tp.src[1] = Wk; tp.src[2] = Wv; tp.src[3] = Wr; tp.src[4] = Wo;
  tp.src[5] = W1; tp.src[6] = W2;
  tp.dst[0] = wtq; tp.dst[1] = wtk; tp.dst[2] = wtv; tp.dst[3] = wtr; tp.dst[4] = wto;
  tp.dst[5] = wt1; tp.dst[6] = wt2;

  // 1) all conversions + transposes + dtype flag in one dispatch (vectorized v2)
  preamble_all<<<7089, 256, 0, stream>>>(tp, x, pe, b1, ub, vb, b2, ln1g, ln1b,
                                         ln2g, ln2b, xb, peb, b1c, ubc, vbc, b2c,
                                         g1c, be1c, g2c, be2c, flag);
  // 2) fused QKV (TN=64, supertile-swizzled: 1728 blocks) + r-proj (72)
  gemm_qkv_rp<<<1800, 256, 0, stream>>>(xb, wtq, peb, wtr, quB, qvB, kbB, vtB, rbB,
                                        ubc, vbc);
  // 3) attention -> d_out scratch
  attn_kernel<<<2304, 512, 0, stream>>>(quB, qvB, kbB, vtB, rbB, atB);
  // 4) Wo + residual — 64x64 tiles: grid (12,96)=1152 blocks
  gemm3<64, 64, 32, 32, F_RES, 1><<<dim3(12, 96), 256, 0, stream>>>(
      atB, wto, y1B, nullptr, xb, B_ * S_, D_, D_);
  ln_kernel<<<B_ * S_ / 4, 256, 0, stream>>>(y1B, g1c, be1c, x1B, flag, 0);
  // 5) FFN1 — 128x64 tiles + supertile swizzle: grid (48,48)=2304 blocks
  gemm3<128, 64, 64, 32, F_BIAS | F_RELU, 2><<<dim3(48, 48), 256, 0, stream>>>(
      x1B, wt1, ffB, b1c, nullptr, B_ * S_, FF_, D_);
  // 6) FFN2 — 64x64 tiles: grid (12,96)=1152 blocks
  gemm3<64, 64, 32, 32, F_BIAS | F_RES, 1><<<dim3(12, 96), 256, 0, stream>>>(
      ffB, wt2, y2B, b2c, x1B, B_ * S_, D_, FF_);
  ln_kernel<<<B_ * S_ / 4, 256, 0, stream>>>(y2B, g2c, be2c, d_out, flag, 1);
}

// Round 13
// 386.460 us; speedup vs baseline: 1.1281x; 1.0327x over previous
//
#include <hip/hip_runtime.h>

typedef unsigned short u16;
typedef __attribute__((ext_vector_type(8))) short short8;
typedef __attribute__((ext_vector_type(4))) float floatx4;

#define B_  16
#define S_  384
#define D_  768
#define H_  12
#define DH_ 64
#define FF_ 3072

__device__ __forceinline__ float b2f(u16 h) { return __uint_as_float(((unsigned)h) << 16); }
__device__ __forceinline__ u16 f2b(float f) {
  unsigned u = __float_as_uint(f);
  u += 0x7fffu + ((u >> 16) & 1u);
  return (u16)(u >> 16);
}

__device__ __forceinline__ void gload16(const u16* g, u16* l) {
  __builtin_amdgcn_global_load_lds(
      (const __attribute__((address_space(1))) unsigned int*)g,
      (__attribute__((address_space(3))) unsigned int*)l, 16, 0, 0);
}

__global__ __launch_bounds__(256) void fill_sentinel(u16* out, int n) {
  int i = blockIdx.x * 256 + threadIdx.x;
  if (i < n) out[i] = 0x42DE;  // bf16 111.0
}

// inline dtype detect: 256 u16 of x; fp32 low-halves hit exp>=0xC0 w.p. 0.25
__device__ __forceinline__ int detect_flag(const u16* x, int tid, int* sh) {
  const unsigned e = (x[tid] >> 7) & 0xFFu;
  const unsigned long long m = __ballot(e >= 0xC0u);
  if ((tid & 63) == 0) sh[tid >> 6] = (m != 0ull) ? 1 : 0;
  __syncthreads();
  return sh[0] | sh[1] | sh[2] | sh[3];
}

// ---------------- mega-preamble v2: VECTORIZED transposes + converts + flag ----------------
struct TP { const void* src[7]; u16* dst[7]; };
__global__ __launch_bounds__(256) void preamble_all(
    TP tp, const void* x, const void* pe,
    const void* b1, const void* ub, const void* vb, const void* b2,
    const void* g1, const void* be1, const void* g2, const void* be2,
    u16* xb, u16* peb,
    u16* b1c, u16* ubc, u16* vbc, u16* b2c,
    u16* g1c, u16* be1c, u16* g2c, u16* be2c, int* flag_ws) {
  __shared__ u16 T[64][68];
  __shared__ int fl[4];
  const int tid = threadIdx.x;
  const int f32 = detect_flag((const u16*)x, tid, fl);
  const int id = blockIdx.x;
  if (id == 0 && tid == 0) *flag_ws = f32;  // for ln_kernel's output dtype

  if (id < 1872) {  // weight transposes, 64x64 vectorized
    int w, tt, R, C, bc, br;
    if (id < 720)       { w = id / 144; tt = id % 144;  R = 768;  C = 768;  bc = (tt % 12) * 64; br = (tt / 12) * 64; }
    else if (id < 1296) { w = 5;        tt = id - 720;  R = 768;  C = 3072; bc = (tt % 48) * 64; br = (tt / 48) * 64; }
    else                { w = 6;        tt = id - 1296; R = 3072; C = 768;  bc = (tt % 12) * 64; br = (tt / 12) * 64; }
    const void* in = tp.src[w];
    u16* out = tp.dst[w];
    const int tx4 = (tid & 15) * 4, ty = tid >> 4;  // ty in [0,16)
#pragma unroll
    for (int p = 0; p < 4; ++p) {
      const int row = ty + p * 16;
      const size_t base = (size_t)(br + row) * C + bc + tx4;
      ushort4 o;
      if (f32) {
        const float4 f = *(const float4*)((const float*)in + base);
        o.x = f2b(f.x); o.y = f2b(f.y); o.z = f2b(f.z); o.w = f2b(f.w);
      } else {
        o = *(const ushort4*)((const u16*)in + base);
      }
      *(ushort4*)&T[row][tx4] = o;
    }
    __syncthreads();
#pragma unroll
    for (int p = 0; p < 4; ++p) {
      const int oc = ty + p * 16;
      ushort4 o;
      o.x = T[tx4 + 0][oc];
      o.y = T[tx4 + 1][oc];
      o.z = T[tx4 + 2][oc];
      o.w = T[tx4 + 3][oc];
      *(ushort4*)(out + (size_t)(bc + oc) * R + br + tx4) = o;
    }
  } else if (id < 6480) {  // x convert (4-wide)
    const int i = (id - 1872) * 256 + tid;
    if (i < B_ * S_ * D_ / 4) {
      if (f32) {
        const float4 f = ((const float4*)x)[i];
        ushort4 o;
        o.x = f2b(f.x); o.y = f2b(f.y); o.z = f2b(f.z); o.w = f2b(f.w);
        ((ushort4*)xb)[i] = o;
      } else {
        ((ushort4*)xb)[i] = ((const ushort4*)x)[i];
      }
    }
  } else if (id < 7056) {  // pe convert
    const int i = (id - 6480) * 256 + tid;
    if (i < (2 * S_ - 1) * D_ / 4) {
      if (f32) {
        const float4 f = ((const float4*)pe)[i];
        ushort4 o;
        o.x = f2b(f.x); o.y = f2b(f.y); o.z = f2b(f.z); o.w = f2b(f.w);
        ((ushort4*)peb)[i] = o;
      } else {
        ((ushort4*)peb)[i] = ((const ushort4*)pe)[i];
      }
    }
  } else {  // small tensors
    const int i = (id - 7056) * 256 + tid;
    if (i < 8448) {
      const void* s; u16* d; int off;
      if (i < 3072) { s = b1; d = b1c; off = i; }
      else {
        const int r = i - 3072, sg = r / 768; off = r - sg * 768;
        switch (sg) {
          case 0: s = ub;  d = ubc;  break;
          case 1: s = vb;  d = vbc;  break;
          case 2: s = b2;  d = b2c;  break;
          case 3: s = g1;  d = g1c;  break;
          case 4: s = be1; d = be1c; break;
          case 5: s = g2;  d = g2c;  break;
          default: s = be2; d = be2c; break;
        }
      }
      d[off] = f32 ? f2b(((const float*)s)[off]) : ((const u16*)s)[off];
    }
  }
}

// ---------------- GEMM v3: XOR-swizzled LDS + prefetch ----------------
enum { F_BIAS = 1, F_RELU = 2, F_RES = 4 };

template <int TM, int TN, int WM, int WN, int FLAGS, int SWZ>
__global__ __launch_bounds__(256) void gemm3(
    const u16* __restrict__ A, const u16* __restrict__ Bt,
    u16* __restrict__ out0, const u16* __restrict__ bias0,
    const u16* __restrict__ res, int M, int N, int K) {
  constexpr int WAVES_M = TM / WM;
  constexpr int MT = WM / 16, NT = WN / 16;
  constexpr int NI = (TM + TN) / 64;
  static_assert((TM / WM) * (TN / WN) == 4, "4 waves");
  __shared__ u16 SM[2][(TM + TN) * 32];

  int bxx = blockIdx.x, byy = blockIdx.y;
  if (SWZ == 1) {
    const int gx = gridDim.x;
    const int nwg = gx * gridDim.y;
    if (!(nwg & 7)) {
      const int q = nwg >> 3;
      const int d = byy * gx + bxx;
      const int id = (d & 7) * q + (d >> 3);
      bxx = id % gx;
      byy = id / gx;
    }
  } else if (SWZ == 2) {
    const int gx = gridDim.x;
    const int SX = gx >> 1, SY = gridDim.y >> 2;
    const int d = byy * gx + bxx;
    const int c = d & 7, r = d >> 3;
    bxx = (c & 1) * SX + r % SX;
    byy = (c >> 1) * SY + r / SX;
  }
  const int m0 = byy * TM;
  const int n0 = bxx * TN;
  const int tid = threadIdx.x;
  const int wid = tid >> 6, lane = tid & 63;
  const int wm = (wid % WAVES_M) * WM, wn = (wid / WAVES_M) * WN;
  const int lm = lane & 15, quad = lane >> 4;

  floatx4 acc[MT][NT];
#pragma unroll
  for (int i = 0; i < MT; ++i)
#pragma unroll
    for (int j = 0; j < NT; ++j) acc[i][j] = (floatx4){0.f, 0.f, 0.f, 0.f};

  const u16* srcs[NI];
  int ldso[NI];
#pragma unroll
  for (int i = 0; i < NI; ++i) {
    const int j = wid + 4 * i;
    const int r = j * 16 + (lane >> 2);
    const int q = (lane & 3) ^ ((r >> 1) & 3);
    const u16* p;
    if (r < TM) {
      int ga = m0 + r;
      if (ga > M - 1) ga = M - 1;
      p = A + (size_t)ga * K + q * 8;
    } else {
      p = Bt + (size_t)(n0 + r - TM) * K + q * 8;
    }
    srcs[i] = p;
    ldso[i] = j * 512;
  }
  const int slot = (quad ^ ((lm >> 1) & 3)) * 8;
  int aoff[MT], boff[NT];
#pragma unroll
  for (int t = 0; t < MT; ++t) aoff[t] = (wm + t * 16 + lm) * 32 + slot;
#pragma unroll
  for (int t = 0; t < NT; ++t) boff[t] = (TM + wn + t * 16 + lm) * 32 + slot;

#pragma unroll
  for (int i = 0; i < NI; ++i) gload16(srcs[i], &SM[0][ldso[i]]);
  __syncthreads();

  int buf = 0;
  for (int k0 = 0; k0 < K; k0 += 32, buf ^= 1) {
    if (k0 + 32 < K) {
      const int koff = (k0 + 32);
#pragma unroll
      for (int i = 0; i < NI; ++i) gload16(srcs[i] + koff, &SM[buf ^ 1][ldso[i]]);
    }
    short8 af[MT], bf[NT];
#pragma unroll
    for (int t = 0; t < MT; ++t) af[t] = *(const short8*)(&SM[buf][aoff[t]]);
#pragma unroll
    for (int t = 0; t < NT; ++t) bf[t] = *(const short8*)(&SM[buf][boff[t]]);
#pragma unroll
    for (int tm = 0; tm < MT; ++tm)
#pragma unroll
      for (int tn = 0; tn < NT; ++tn)
        acc[tm][tn] = __builtin_amdgcn_mfma_f32_16x16x32_bf16(af[tm], bf[tn], acc[tm][tn], 0, 0, 0);
    __syncthreads();
  }

#pragma unroll
  for (int tm = 0; tm < MT; ++tm) {
#pragma unroll
    for (int tn = 0; tn < NT; ++tn) {
      const int gcol = n0 + wn + tn * 16 + lm;
#pragma unroll
      for (int r = 0; r < 4; ++r) {
        const int grow = m0 + wm + tm * 16 + quad * 4 + r;
        if (grow >= M) continue;
        float val = acc[tm][tn][r];
        if (FLAGS & F_BIAS) val += b2f(bias0[gcol]);
        if (FLAGS & F_RES) val += b2f(res[(size_t)grow * N + gcol]);
        if (FLAGS & F_RELU) val = fmaxf(val, 0.f);
        out0[(size_t)grow * N + gcol] = f2b(val);
      }
    }
  }
}

// ---------------- fused QKV (region epilogue + fragment-linear vt) + r-proj ----------------
// vt layout v2 (fragment-linear, for coalesced attn phase-3 reads):
//   element (b, d, s) at offset ((b*12 + s/32)*768 + d)*32 + (s%32).
// A phase-3 wave-load then covers 1 KB contiguous (lm-lanes at 64-B stride).
__global__ __launch_bounds__(256) void gemm_qkv_rp(
    const u16* __restrict__ xb, const u16* __restrict__ wqkv,
    const u16* __restrict__ peb, const u16* __restrict__ wtr,
    u16* __restrict__ qu, u16* __restrict__ qv,
    u16* __restrict__ kbo, u16* __restrict__ vto, u16* __restrict__ rbo,
    const u16* __restrict__ ubias, const u16* __restrict__ vbias) {
  constexpr int TM = 128, TN = 64, WM = 64, WN = 32;
  constexpr int MT = 4, NT = 2, NI = 3;
  __shared__ u16 SM[2][(TM + TN) * 32];

  const int id = blockIdx.x;
  const int qkv = (id < 1728) ? 1 : 0;
  int bx, by, M;
  const u16 *A, *Bt;
  if (qkv) {
    // supertile: XCD c = id%8 gets subtile (c&1, c>>1) of 18x12 blocks
    const int c = id & 7, r = id >> 3;  // r in [0,216)
    bx = (c & 1) * 18 + r % 18;
    by = (c >> 1) * 12 + r / 18;
    M = B_ * S_; A = xb; Bt = wqkv;
  } else {
    const int t2 = id - 1728; bx = t2 % 12; by = t2 / 12; M = 767; A = peb; Bt = wtr;
  }
  const int K = 768;
  const int m0 = by * TM, n0 = bx * TN;
  const int tid = threadIdx.x;
  const int wid = tid >> 6, lane = tid & 63;
  const int wm = (wid & 1) * WM, wn = (wid >> 1) * WN;
  const int lm = lane & 15, quad = lane >> 4;

  floatx4 acc[MT][NT];
#pragma unroll
  for (int i = 0; i < MT; ++i)
#pragma unroll
    for (int j = 0; j < NT; ++j) acc[i][j] = (floatx4){0.f, 0.f, 0.f, 0.f};

  const u16* srcs[NI];
  int ldso[NI];
#pragma unroll
  for (int i = 0; i < NI; ++i) {
    const int j = wid + 4 * i;
    const int r = j * 16 + (lane >> 2);
    const int q = (lane & 3) ^ ((r >> 1) & 3);
    const u16* p;
    if (r < TM) {
      int ga = m0 + r;
      if (ga > M - 1) ga = M - 1;
      p = A + (size_t)ga * K + q * 8;
    } else {
      p = Bt + (size_t)(n0 + r - TM) * K + q * 8;
    }
    srcs[i] = p;
    ldso[i] = j * 512;
  }
  const int slot = (quad ^ ((lm >> 1) & 3)) * 8;
  int aoff[MT], boff[NT];
#pragma unroll
  for (int t = 0; t < MT; ++t) aoff[t] = (wm + t * 16 + lm) * 32 + slot;
#pragma unroll
  for (int t = 0; t < NT; ++t) boff[t] = (TM + wn + t * 16 + lm) * 32 + slot;

#pragma unroll
  for (int i = 0; i < NI; ++i) gload16(srcs[i], &SM[0][ldso[i]]);
  __syncthreads();

  int buf = 0;
  for (int k0 = 0; k0 < K; k0 += 32, buf ^= 1) {
    if (k0 + 32 < K) {
      const int koff = (k0 + 32);
#pragma unroll
      for (int i = 0; i < NI; ++i) gload16(srcs[i] + koff, &SM[buf ^ 1][ldso[i]]);
    }
    short8 af[MT], bf[NT];
#pragma unroll
    for (int t = 0; t < MT; ++t) af[t] = *(const short8*)(&SM[buf][aoff[t]]);
#pragma unroll
    for (int t = 0; t < NT; ++t) bf[t] = *(const short8*)(&SM[buf][boff[t]]);
#pragma unroll
    for (int tm = 0; tm < MT; ++tm)
#pragma unroll
      for (int tn = 0; tn < NT; ++tn)
        acc[tm][tn] = __builtin_amdgcn_mfma_f32_16x16x32_bf16(af[tm], bf[tn], acc[tm][tn], 0, 0, 0);
    __syncthreads();
  }

  if (!qkv) {  // r-proj plain store
#pragma unroll
    for (int tm = 0; tm < MT; ++tm)
#pragma unroll
      for (int tn = 0; tn < NT; ++tn) {
        const int gcol = n0 + wn + tn * 16 + lm;
#pragma unroll
        for (int r = 0; r < 4; ++r) {
          const int grow = m0 + wm + tm * 16 + quad * 4 + r;
          if (grow < M) rbo[(size_t)grow * 768 + gcol] = f2b(acc[tm][tn][r]);
        }
      }
    return;
  }
  // QKV epilogue; region is block-uniform (768 % 64 == 0)
  const int region = n0 / 768;
  if (region == 2) {
    // vt: fragment-linear store via per-wave LDS bounce (SM dead after last barrier)
    u16* wbuf = &SM[0][0] + wid * 1088;  // [64][17]
    const int bb = (m0 + wm) / S_;
    const int sbase = (m0 + wm) % S_;    // multiple of 64
    const int cl = lane >> 2, sc = (lane & 3) * 16;
    const int s0abs = sbase + sc;        // multiple of 16
    const int s5 = s0abs >> 5, s3 = s0abs & 31;
#pragma unroll
    for (int tn = 0; tn < NT; ++tn) {
#pragma unroll
      for (int tm = 0; tm < MT; ++tm)
#pragma unroll
        for (int r = 0; r < 4; ++r)
          wbuf[(tm * 16 + quad * 4 + r) * 17 + lm] = f2b(acc[tm][tn][r]);
      short8 s0, s1;
#pragma unroll
      for (int j = 0; j < 8; ++j) s0[j] = (short)wbuf[(sc + j) * 17 + cl];
#pragma unroll
      for (int j = 0; j < 8; ++j) s1[j] = (short)wbuf[(sc + 8 + j) * 17 + cl];
      const int cglob = n0 - 1536 + wn + tn * 16 + cl;  // d in [0,768)
      u16* dst = vto + ((size_t)(bb * 12 + s5) * 768 + cglob) * 32 + s3;
      *(short8*)dst = s0;
      *(short8*)(dst + 8) = s1;
    }
    return;
  }
#pragma unroll
  for (int tm = 0; tm < MT; ++tm) {
#pragma unroll
    for (int tn = 0; tn < NT; ++tn) {
      const int gcol = n0 + wn + tn * 16 + lm;
      const int c = gcol - region * 768;
#pragma unroll
      for (int r = 0; r < 4; ++r) {
        const int grow = m0 + wm + tm * 16 + quad * 4 + r;
        const float val = acc[tm][tn][r];
        if (region == 0) {
          qu[(size_t)grow * 768 + c] = f2b(val + b2f(ubias[c]));
          qv[(size_t)grow * 768 + c] = f2b(val + b2f(vbias[c]));
        } else {
          kbo[(size_t)grow * 768 + c] = f2b(val);
        }
      }
    }
  }
}

// ---------------- attention v15: v14 + coalesced fragment-linear vt reads ----------------
// v14's phase-3 vt loads were 16-line gathers (768-B lane stride). With vt in
// fragment-linear layout, each wave-load is 1 KB contiguous. Rest identical to v14.
// LDS: scB 26112 + rp 1024 + rsum 128 = 27264 B.
__global__ __launch_bounds__(512, 6) void attn_kernel(
    const u16* __restrict__ qu, const u16* __restrict__ qv,
    const u16* __restrict__ kb, const u16* __restrict__ vt,
    const u16* __restrict__ rb, u16* __restrict__ attn) {
  __shared__ u16 scB[32 * 408];   // B_D scatter, then P (bf16) in place
  __shared__ float rp[32][8];     // per-wave row-sum partials
  __shared__ float rsum[32];

  const int id = blockIdx.x;
  const int g = id >> 3;
  const int qt = g % 12;
  const int bh = (id & 7) + 8 * (g / 12);
  const int b = bh / H_, h = bh % H_;
  const int i0 = qt * 32;
  const int tid = threadIdx.x, wid = tid >> 6, lane = tid & 63;
  const int lm = lane & 15, quad = lane >> 4;

  const size_t qr0 = ((size_t)(b * S_ + i0 + lm)) * D_ + h * DH_;
  const size_t qr1 = qr0 + (size_t)16 * D_;

  // ---- Q fragments: time-shared registers (qv for loop A, qu for loop B) ----
  short8 q0a = *(const short8*)(qv + qr0 + quad * 8);
  short8 q0b = *(const short8*)(qv + qr0 + 32 + quad * 8);
  short8 q1a = *(const short8*)(qv + qr1 + quad * 8);
  short8 q1b = *(const short8*)(qv + qr1 + 32 + quad * 8);

  // pre-issue first kb unit load (j = wid): in flight during all of loop A
  const u16* kbase = kb + ((size_t)(b * S_ + lm)) * D_ + h * DH_ + quad * 8;
  short8 k0, k1;
  {
    const u16* p = kbase + (size_t)wid * 16 * D_;
    k0 = *(const short8*)p;
    k1 = *(const short8*)(p + 32);
  }

  // ---- loop A: rb units (B_D) -> scatter into scB at reversed positions ----
  short8 b0, b1;
  {
    // first unit m = wid (<8): t <= 479 < 766, no clamp needed
    const int t = i0 + 16 * wid + lm;
    const u16* p = rb + (size_t)t * D_ + h * DH_ + quad * 8;
    b0 = *(const short8*)p;
    b1 = *(const short8*)(p + 32);
  }
  for (int m = wid; m < 26; m += 8) {
    short8 n0 = b0, n1 = b1;
    const int mn = m + 8;
    if (mn < 26) {
      int t = i0 + 16 * mn + lm;
      if (t > 766) t = 766;
      const u16* pn = rb + (size_t)t * D_ + h * DH_ + quad * 8;
      n0 = *(const short8*)pn;
      n1 = *(const short8*)(pn + 32);
    }
    if (m <= 24) {
      floatx4 e = (floatx4){0.f, 0.f, 0.f, 0.f};
      e = __builtin_amdgcn_mfma_f32_16x16x32_bf16(q0a, b0, e, 0, 0, 0);
      e = __builtin_amdgcn_mfma_f32_16x16x32_bf16(q0b, b1, e, 0, 0, 0);
#pragma unroll
      for (int r = 0; r < 4; ++r) {
        const int row = quad * 4 + r;
        const int cp = row + 383 - (16 * m + lm);   // e-idx = 16m+lm
        if (cp >= 0) scB[row * 408 + cp] = f2b(e[r]);
      }
    }
    if (m >= 1) {
      floatx4 e = (floatx4){0.f, 0.f, 0.f, 0.f};
      e = __builtin_amdgcn_mfma_f32_16x16x32_bf16(q1a, b0, e, 0, 0, 0);
      e = __builtin_amdgcn_mfma_f32_16x16x32_bf16(q1b, b1, e, 0, 0, 0);
#pragma unroll
      for (int r = 0; r < 4; ++r) {
        const int row = quad * 4 + r;                // row&15 of (16+row)
        const int cp = row + 399 - 16 * m - lm;      // e-idx = 16(m-1)+lm
        if (cp >= 0) scB[(16 + row) * 408 + cp] = f2b(e[r]);
      }
    }
    b0 = n0;
    b1 = n1;
  }

  // ---- swap Q fragments: qu replaces qv in the same registers ----
  q0a = *(const short8*)(qu + qr0 + quad * 8);
  q0b = *(const short8*)(qu + qr0 + 32 + quad * 8);
  q1a = *(const short8*)(qu + qr1 + quad * 8);
  q1b = *(const short8*)(qu + qr1 + 32 + quad * 8);

  __syncthreads();  // barrier 0: all B_D scatter complete before A_C RMW

  // ---- loop B: kb units (A_C) + fused softmax: P written in place ----
  float psum[8];
#pragma unroll
  for (int r = 0; r < 8; ++r) psum[r] = 0.f;
  b0 = k0;
  b1 = k1;
  for (int j = wid; j < 24; j += 8) {
    short8 n0 = b0, n1 = b1;
    const int jn = j + 8;
    if (jn < 24) {
      const u16* pn = kbase + (size_t)jn * 16 * D_;
      n0 = *(const short8*)pn;
      n1 = *(const short8*)(pn + 32);
    }
    floatx4 e0 = (floatx4){0.f, 0.f, 0.f, 0.f};
    e0 = __builtin_amdgcn_mfma_f32_16x16x32_bf16(q0a, b0, e0, 0, 0, 0);
    e0 = __builtin_amdgcn_mfma_f32_16x16x32_bf16(q0b, b1, e0, 0, 0, 0);
    floatx4 e1 = (floatx4){0.f, 0.f, 0.f, 0.f};
    e1 = __builtin_amdgcn_mfma_f32_16x16x32_bf16(q1a, b0, e1, 0, 0, 0);
    e1 = __builtin_amdgcn_mfma_f32_16x16x32_bf16(q1b, b1, e1, 0, 0, 0);
    const int c = 16 * j + lm;
#pragma unroll
    for (int r = 0; r < 4; ++r) {
      const int o0 = (quad * 4 + r) * 408 + c;
      const int o1 = (16 + quad * 4 + r) * 408 + c;
      const float p0 = __expf((e0[r] + b2f(scB[o0])) * 0.125f);
      scB[o0] = f2b(p0);
      psum[r] += p0;
      const float p1 = __expf((e1[r] + b2f(scB[o1])) * 0.125f);
      scB[o1] = f2b(p1);
      psum[4 + r] += p1;
    }
    b0 = n0;
    b1 = n1;
  }
  // reduce psum over the 16-lane quad group (rows are quad-owned within wave)
#pragma unroll
  for (int m = 1; m < 16; m <<= 1) {
#pragma unroll
    for (int r = 0; r < 8; ++r) psum[r] += __shfl_xor(psum[r], m);
  }
  if (lm == 0) {
#pragma unroll
    for (int r = 0; r < 4; ++r) {
      rp[quad * 4 + r][wid] = psum[r];
      rp[16 + quad * 4 + r][wid] = psum[4 + r];
    }
  }

  __syncthreads();  // barrier 1: P and rp complete

  // ---- mini-pass: finish row sums across the 8 waves ----
  if (tid < 32) {
    float s = 0.f;
#pragma unroll
    for (int w = 0; w < 8; ++w) s += rp[tid][w];
    rsum[tid] = s;
  }
  __syncthreads();  // barrier 2

  // ---- phase 3: PV; vt reads are fragment-linear (1 KB contiguous per wave) ----
  {
    const int rg = wid & 1, nt = wid >> 1;
    // vt2 offset: ((b*12 + kk)*768 + d)*32 + (s%32), d = h*64 + nt*16 + lm
    const size_t vbase = ((size_t)(b * 12) * 768 + h * DH_ + nt * 16 + lm) * 32 + quad * 8;
    floatx4 oA = (floatx4){0.f, 0.f, 0.f, 0.f};
    floatx4 oB = (floatx4){0.f, 0.f, 0.f, 0.f};
    const int pbase = (rg * 16 + lm) * 408;
#pragma unroll
    for (int kk = 0; kk < 12; kk += 2) {
      const short8 bvA = *(const short8*)(vt + vbase + (size_t)kk * 24576);
      const short8 afA = *(const short8*)(&scB[pbase + kk * 32 + quad * 8]);
      oA = __builtin_amdgcn_mfma_f32_16x16x32_bf16(afA, bvA, oA, 0, 0, 0);
      const short8 bvB = *(const short8*)(vt + vbase + (size_t)(kk + 1) * 24576);
      const short8 afB = *(const short8*)(&scB[pbase + (kk + 1) * 32 + quad * 8]);
      oB = __builtin_amdgcn_mfma_f32_16x16x32_bf16(afB, bvB, oB, 0, 0, 0);
    }
#pragma unroll
    for (int r = 0; r < 4; ++r) {
      const int row = rg * 16 + quad * 4 + r;
      attn[((size_t)(b * S_ + i0 + row)) * D_ + h * DH_ + nt * 16 + lm] =
          f2b((oA[r] + oB[r]) / rsum[row]);
    }
  }
}

// ---------------- row layernorm (vectorized: 3x ushort4 per lane) ----------------
__global__ __launch_bounds__(256) void ln_kernel(const u16* __restrict__ y,
                                                 const u16* __restrict__ g,
                                                 const u16* __restrict__ bb,
                                                 void* __restrict__ outv,
                                                 const int* __restrict__ flag, int dual) {
  const int row = blockIdx.x * 4 + (threadIdx.x >> 6);
  const int lane = threadIdx.x & 63;
  const int c0 = lane * 12;
  const u16* yr = y + (size_t)row * D_ + c0;
  float vbuf[12], s = 0.f, s2 = 0.f;
#pragma unroll
  for (int t = 0; t < 3; ++t) {
    const ushort4 v = *(const ushort4*)(yr + t * 4);
    vbuf[t * 4 + 0] = b2f(v.x);
    vbuf[t * 4 + 1] = b2f(v.y);
    vbuf[t * 4 + 2] = b2f(v.z);
    vbuf[t * 4 + 3] = b2f(v.w);
  }
#pragma unroll
  for (int i = 0; i < 12; ++i) {
    s += vbuf[i];
    s2 += vbuf[i] * vbuf[i];
  }
#pragma unroll
  for (int off = 32; off; off >>= 1) {
    s += __shfl_down(s, off);
    s2 += __shfl_down(s2, off);
  }
  s = __shfl(s, 0);
  s2 = __shfl(s2, 0);
  const float mean = s * (1.f / 768.f);
  const float var = s2 * (1.f / 768.f) - mean * mean;
  const float inv = rsqrtf(var + 1e-5f);
  const int f32out = dual && *flag;
  float o[12];
#pragma unroll
  for (int t = 0; t < 3; ++t) {
    const ushort4 gv = *(const ushort4*)(g + c0 + t * 4);
    const ushort4 bv = *(const ushort4*)(bb + c0 + t * 4);
    o[t * 4 + 0] = (vbuf[t * 4 + 0] - mean) * inv * b2f(gv.x) + b2f(bv.x);
    o[t * 4 + 1] = (vbuf[t * 4 + 1] - mean) * inv * b2f(gv.y) + b2f(bv.y);
    o[t * 4 + 2] = (vbuf[t * 4 + 2] - mean) * inv * b2f(gv.z) + b2f(bv.z);
    o[t * 4 + 3] = (vbuf[t * 4 + 3] - mean) * inv * b2f(gv.w) + b2f(bv.w);
  }
  if (f32out) {
    float* dst = (float*)outv + (size_t)row * D_ + c0;
#pragma unroll
    for (int t = 0; t < 3; ++t) {
      float4 f;
      f.x = o[t * 4 + 0]; f.y = o[t * 4 + 1]; f.z = o[t * 4 + 2]; f.w = o[t * 4 + 3];
      *(float4*)(dst + t * 4) = f;
    }
  } else {
    u16* dst = (u16*)outv + (size_t)row * D_ + c0;
#pragma unroll
    for (int t = 0; t < 3; ++t) {
      ushort4 u;
      u.x = f2b(o[t * 4 + 0]); u.y = f2b(o[t * 4 + 1]);
      u.z = f2b(o[t * 4 + 2]); u.w = f2b(o[t * 4 + 3]);
      *(ushort4*)(dst + t * 4) = u;
    }
  }
}

// ---------------- host ----------------
extern "C" void kernel_launch(void* const* d_in, const int* in_sizes, int n_in,
                              void* d_out, int out_size, void* d_ws, size_t ws_size,
                              hipStream_t stream) {
  const void* x    = d_in[0];
  const void* pe   = d_in[1];
  const void* Wq   = d_in[2];
  const void* Wk   = d_in[3];
  const void* Wv   = d_in[4];
  const void* Wr   = d_in[5];
  const void* ub   = d_in[6];
  const void* vb   = d_in[7];
  const void* Wo   = d_in[8];
  const void* ln1g = d_in[9];
  const void* ln1b = d_in[10];
  const void* ln2g = d_in[11];
  const void* ln2b = d_in[12];
  const void* W1   = d_in[13];
  const void* b1   = d_in[14];
  const void* W2   = d_in[15];
  const void* b2   = d_in[16];
  char* ws = (char*)d_ws;

  constexpr size_t O_W   = 0;
  constexpr size_t O_SM  = 15335424;
  constexpr size_t O_XB  = 15368192;
  constexpr size_t O_QU  = 24805376;
  constexpr size_t O_QV  = 34242560;
  constexpr size_t O_KB  = 43679744;
  constexpr size_t O_VT  = 53116928;
  constexpr size_t O_RB  = 62554112;
  constexpr size_t NEEDED = 63733760;

  if (ws_size < NEEDED) {
    fill_sentinel<<<(out_size + 255) / 256, 256, 0, stream>>>((u16*)d_out, out_size);
    return;
  }

  int* flag = (int*)(ws + O_SM);
  u16* ubc  = (u16*)(ws + O_SM + 128);
  u16* vbc  = (u16*)(ws + O_SM + 1664);
  u16* b1c  = (u16*)(ws + O_SM + 3200);
  u16* b2c  = (u16*)(ws + O_SM + 9344);
  u16* g1c  = (u16*)(ws + O_SM + 10880);
  u16* be1c = (u16*)(ws + O_SM + 12416);
  u16* g2c  = (u16*)(ws + O_SM + 13952);
  u16* be2c = (u16*)(ws + O_SM + 15488);

  u16* wtq = (u16*)(ws + O_W);   // wtq|wtk|wtv contiguous = fused QKV B
  u16* wtk = wtq + (size_t)D_ * D_;
  u16* wtv = wtk + (size_t)D_ * D_;
  u16* wtr = wtv + (size_t)D_ * D_;
  u16* wto = wtr + (size_t)D_ * D_;
  u16* wt1 = wto + (size_t)D_ * D_;
  u16* wt2 = wt1 + (size_t)D_ * FF_;

  u16* xb  = (u16*)(ws + O_XB);
  u16* quB = (u16*)(ws + O_QU);
  u16* qvB = (u16*)(ws + O_QV);
  u16* kbB = (u16*)(ws + O_KB);
  u16* vtB = (u16*)(ws + O_VT);
  u16* rbB = (u16*)(ws + O_RB);
  u16* peb = (u16*)d_out;          // pe lives in d_out until QKV+rproj completes
  u16* atB = (u16*)d_out;          // attn out overwrites peb afterwards (serial)
  u16* y1B = xb;
  u16* x1B = (u16*)(ws + O_VT);
  u16* ffB = xb;
  u16* y2B = x1B;

  TP tp;
  tp.src[0] = Wq; tp.src[1] = Wk; tp.src[2] = Wv; tp.src[3] = Wr; tp.src[4] = Wo;
  tp.src[5] = W1; tp.src[6] = W2;
  tp.dst[0] = wtq; tp.dst[1] = wtk; tp.dst[2] = wtv; tp.dst[3] = wtr; tp.dst[4] = wto;
  tp.dst[5] = wt1; tp.dst[6] = wt2;

  // 1) all conversions + transposes + dtype flag in one dispatch (vectorized v2)
  preamble_all<<<7089, 256, 0, stream>>>(tp, x, pe, b1, ub, vb, b2, ln1g, ln1b,
                                         ln2g, ln2b, xb, peb, b1c, ubc, vbc, b2c,
                                         g1c, be1c, g2c, be2c, flag);
  // 2) fused QKV (TN=64, supertile-swizzled: 1728 blocks) + r-proj (72)
  gemm_qkv_rp<<<1800, 256, 0, stream>>>(xb, wtq, peb, wtr, quB, qvB, kbB, vtB, rbB,
                                        ubc, vbc);
  // 3) attention -> d_out scratch
  attn_kernel<<<2304, 512, 0, stream>>>(quB, qvB, kbB, vtB, rbB, atB);
  // 4) Wo + residual — 64x64 tiles: grid (12,96)=1152 blocks
  gemm3<64, 64, 32, 32, F_RES, 1><<<dim3(12, 96), 256, 0, stream>>>(
      atB, wto, y1B, nullptr, xb, B_ * S_, D_, D_);
  ln_kernel<<<B_ * S_ / 4, 256, 0, stream>>>(y1B, g1c, be1c, x1B, flag, 0);
  // 5) FFN1 — 128x64 tiles + supertile swizzle: grid (48,48)=2304 blocks
  gemm3<128, 64, 64, 32, F_BIAS | F_RELU, 2><<<dim3(48, 48), 256, 0, stream>>>(
      x1B, wt1, ffB, b1c, nullptr, B_ * S_, FF_, D_);
  // 6) FFN2 — 64x64 tiles: grid (12,96)=1152 blocks
  gemm3<64, 64, 32, 32, F_BIAS | F_RES, 1><<<dim3(12, 96), 256, 0, stream>>>(
      ffB, wt2, y2B, b2c, x1B, B_ * S_, D_, FF_);
  ln_kernel<<<B_ * S_ / 4, 256, 0, stream>>>(y2B, g2c, be2c, d_out, flag, 1);
}